// Round 6
// baseline (311.475 us; speedup 1.0000x reference)
//
#include <hip/hip_runtime.h>

typedef __bf16 bf16x8 __attribute__((ext_vector_type(8)));
typedef __bf16 bf16x4 __attribute__((ext_vector_type(4)));
typedef float f32x4 __attribute__((ext_vector_type(4)));
typedef unsigned short u16;

#if __has_builtin(__builtin_amdgcn_exp2f)
#define EXP2(x) __builtin_amdgcn_exp2f(x)
#else
#define EXP2(x) exp2f(x)
#endif

__device__ __forceinline__ float bf2f(u16 u){
    union { unsigned int i; float f; } x; x.i = ((unsigned int)u) << 16; return x.f;
}
__device__ __forceinline__ u16 f2bf(float f){
    union { float f; unsigned int i; } x; x.f = f;
    unsigned int r = x.i + 0x7fff + ((x.i >> 16) & 1);
    return (u16)(r >> 16);
}
__device__ __forceinline__ int4 cvt8(const float4 a, const float4 b){
    union { u16 h[8]; int4 v; } u;
    u.h[0] = f2bf(a.x); u.h[1] = f2bf(a.y); u.h[2] = f2bf(a.z); u.h[3] = f2bf(a.w);
    u.h[4] = f2bf(b.x); u.h[5] = f2bf(b.y); u.h[6] = f2bf(b.z); u.h[7] = f2bf(b.w);
    return u.v;
}

// ---------------------------------------------------------------------------
// Transpose 4 x [1024][1024] f32 weights -> bf16 Wt [N][K]
// ---------------------------------------------------------------------------
__global__ __launch_bounds__(256) void transpose4(
    const float* __restrict__ w0, const float* __restrict__ w1,
    const float* __restrict__ w2, const float* __restrict__ w3,
    u16* __restrict__ out)
{
    __shared__ float tile[32][33];
    int mat = blockIdx.z;
    const float* in = (mat == 0) ? w0 : (mat == 1) ? w1 : (mat == 2) ? w2 : w3;
    u16* o = out + (size_t)mat * 1048576;
    int bx = blockIdx.x * 32, by = blockIdx.y * 32;
    int tx = threadIdx.x & 31, ty = threadIdx.x >> 5; // 32 x 8
    #pragma unroll
    for (int i = 0; i < 32; i += 8)
        tile[ty + i][tx] = in[(size_t)(by + ty + i) * 1024 + bx + tx];
    __syncthreads();
    #pragma unroll
    for (int i = 0; i < 32; i += 8)
        o[(size_t)(bx + ty + i) * 1024 + by + tx] = f2bf(tile[tx][ty + i]);
}

// ---------------------------------------------------------------------------
// GEMM: C = A(8192x1024) * Bt(1024x1024)^T + bias, store per MODE
// AF32: A is f32 (converted to bf16 during LDS staging); else A is bf16.
// MODE 0: Q/K -> [b][h][q][d] bf16 (scaled)   MODE 1: V -> [b][h][d][q] bf16
// MODE 2: f32 row-major + f32 residual
// ---------------------------------------------------------------------------
template<int MODE, bool AF32>
__global__ __launch_bounds__(256) void gemm_bt(
    const void* __restrict__ Av, const u16* __restrict__ Bt,
    const float* __restrict__ bias, const float* __restrict__ resid,
    void* __restrict__ Cv, float scale)
{
    constexpr int K = 1024;
    __shared__ alignas(16) u16 As[2][128][32];
    __shared__ alignas(16) u16 Bs[2][128][32];
    const int tid = threadIdx.x;
    const int lane = tid & 63, wid = tid >> 6;
    const int wm = wid >> 1, wn = wid & 1;
    const int m0 = blockIdx.x * 128, n0 = blockIdx.y * 128;
    const int r0 = tid >> 2;            // 0..63
    const int kc = (tid & 3) * 8;       // 0,8,16,24
    const int fr = lane & 15, fk = (lane >> 4) * 8;

    const float* Af0 = (const float*)Av + (size_t)(m0 + r0) * K + kc;
    const float* Af1 = Af0 + (size_t)64 * K;
    const u16*   Ah0 = (const u16*)Av + (size_t)(m0 + r0) * K + kc;
    const u16*   Ah1 = Ah0 + (size_t)64 * K;
    const u16* Brow0 = Bt + (size_t)(n0 + r0) * K + kc;
    const u16* Brow1 = Brow0 + (size_t)64 * K;

    int4 pa0, pa1, pb0, pb1;
    if constexpr (AF32) {
        pa0 = cvt8(((const float4*)Af0)[0], ((const float4*)Af0)[1]);
        pa1 = cvt8(((const float4*)Af1)[0], ((const float4*)Af1)[1]);
    } else {
        pa0 = *(const int4*)(Ah0);
        pa1 = *(const int4*)(Ah1);
    }
    pb0 = *(const int4*)(Brow0);
    pb1 = *(const int4*)(Brow1);
    *(int4*)&As[0][r0][kc]      = pa0;
    *(int4*)&As[0][r0 + 64][kc] = pa1;
    *(int4*)&Bs[0][r0][kc]      = pb0;
    *(int4*)&Bs[0][r0 + 64][kc] = pb1;
    __syncthreads();

    f32x4 acc[4][4] = {};
    constexpr int NT = K / 32;
    for (int t = 0; t < NT; ++t) {
        int cur = t & 1, nxt = cur ^ 1;
        if (t + 1 < NT) {
            if constexpr (AF32) {
                pa0 = cvt8(((const float4*)(Af0 + (t + 1) * 32))[0],
                           ((const float4*)(Af0 + (t + 1) * 32))[1]);
                pa1 = cvt8(((const float4*)(Af1 + (t + 1) * 32))[0],
                           ((const float4*)(Af1 + (t + 1) * 32))[1]);
            } else {
                pa0 = *(const int4*)(Ah0 + (t + 1) * 32);
                pa1 = *(const int4*)(Ah1 + (t + 1) * 32);
            }
            pb0 = *(const int4*)(Brow0 + (t + 1) * 32);
            pb1 = *(const int4*)(Brow1 + (t + 1) * 32);
        }
        bf16x8 af[4], bfr[4];
        #pragma unroll
        for (int i = 0; i < 4; i++) {
            af[i]  = *(const bf16x8*)&As[cur][wm * 64 + i * 16 + fr][fk];
            bfr[i] = *(const bf16x8*)&Bs[cur][wn * 64 + i * 16 + fr][fk];
        }
        #pragma unroll
        for (int mi = 0; mi < 4; mi++)
            #pragma unroll
            for (int ni = 0; ni < 4; ni++)
                acc[mi][ni] = __builtin_amdgcn_mfma_f32_16x16x32_bf16(
                    af[mi], bfr[ni], acc[mi][ni], 0, 0, 0);
        if (t + 1 < NT) {
            *(int4*)&As[nxt][r0][kc]      = pa0;
            *(int4*)&As[nxt][r0 + 64][kc] = pa1;
            *(int4*)&Bs[nxt][r0][kc]      = pb0;
            *(int4*)&Bs[nxt][r0 + 64][kc] = pb1;
        }
        __syncthreads();
    }

    #pragma unroll
    for (int ni = 0; ni < 4; ni++) {
        int col = n0 + wn * 64 + ni * 16 + fr;
        float bcol = bias[col];
        #pragma unroll
        for (int mi = 0; mi < 4; mi++) {
            #pragma unroll
            for (int r = 0; r < 4; r++) {
                int m = m0 + wm * 64 + mi * 16 + (lane >> 4) * 4 + r;
                float val = acc[mi][ni][r] + bcol;
                if (MODE == 2) {
                    val += resid[(size_t)m * 1024 + col];
                    ((float*)Cv)[(size_t)m * 1024 + col] = val;
                } else {
                    val *= scale;
                    int b = m >> 11, q = m & 2047;
                    int h = col >> 6, d = col & 63;
                    size_t base = (size_t)(b * 16 + h) * 131072;
                    if (MODE == 0) ((u16*)Cv)[base + (size_t)q * 64 + d] = f2bf(val);
                    else           ((u16*)Cv)[base + (size_t)d * 2048 + q] = f2bf(val);
                }
            }
        }
    }
}

// ---------------------------------------------------------------------------
// Flash attention v5: swapped QK^T, XOR-swizzled LDS, QBLK=128, exp2-domain
// softmax-lite, per-lane deferred row-sum, K/V double-buffer, setprio,
// XCD-bijective swizzle. LDS trimmed to exactly 40960 B (Pl time-shared
// 2KB/wave, mask flags in registers) -> 4 blocks/CU, whole grid co-resident.
// Qp/Kp [bh][2048][64] (Q pre-scaled by 1/8*log2e), Vt [bh][64][2048]
// -> O [b][q][h*64+d] bf16
// ---------------------------------------------------------------------------
__global__ __launch_bounds__(256, 4) void attn_k(
    const u16* __restrict__ Qp, const u16* __restrict__ Kp,
    const u16* __restrict__ Vt, const int* __restrict__ mask,
    u16* __restrict__ O)
{
    __shared__ alignas(16) u16 Ks[2][64][64];   // [buf][kv][d], swizzled (16 KB)
    __shared__ alignas(16) u16 Vs[2][64][64];   // [buf][d][kv], swizzled (16 KB)
    __shared__ alignas(16) u16 Pl[4][16][64];   // per-wave 2KB P bounce (8 KB)

    // XCD-bijective swizzle: all 16 q-tiles of one bh share blockIdx%8 (same XCD)
    const int wg = blockIdx.x;                 // 0..1023
    const int xc = wg & 7;
    const int rm = wg >> 3;                    // 0..127
    const int qx = rm & 15;
    const int bh = (rm >> 4) * 8 + xc;         // bijective
    const int b = bh >> 4, h = bh & 15;
    const int q0 = qx * 128;
    const int tid = threadIdx.x, wid = tid >> 6, lane = tid & 63;
    const int ql = lane & 15, g = lane >> 4;
    const int qw = q0 + wid * 32;

    const u16* Qbh = Qp + (size_t)bh * 131072;
    const u16* Kbh = Kp + (size_t)bh * 131072;
    const u16* Vbh = Vt + (size_t)bh * 131072;
    const int* mrow = mask + b * 2048;

    char* KsB0 = (char*)Ks;
    char* VsB0 = (char*)Vs;
    char* PlB = (char*)Pl + wid * 2048;

    // Q fragments (B-operand layout): qf[fi][ks], q = qw + fi*16 + ql
    bf16x8 qf[2][2];
    #pragma unroll
    for (int fi = 0; fi < 2; fi++)
        #pragma unroll
        for (int ks = 0; ks < 2; ks++)
            qf[fi][ks] = *(const bf16x8*)&Qbh[(size_t)(qw + fi * 16 + ql) * 64 + ks * 32 + g * 8];

    f32x4 oacc[2][4] = {};
    float lrow[2] = {0.f, 0.f};               // per-lane partial row-sums
    const f32x4 kZero = {0.f, 0.f, 0.f, 0.f}; // persistent zero C operand

    // loop-invariant P LDS offsets (per-wave [16][64] buffer, row = ql)
    int pwoff[4], proff[2];
    #pragma unroll
    for (int kb = 0; kb < 4; kb++)
        pwoff[kb] = ql * 128 + ((kb * 32 + g * 8) ^ ((ql & 7) << 4));
    #pragma unroll
    for (int ks = 0; ks < 2; ks++)
        proff[ks] = ql * 128 + ((ks * 64 + g * 16) ^ ((ql & 7) << 4));

    const int sr  = tid >> 3;          // staging row 0..31 (x2)
    const int scb = (tid & 7) * 16;    // staging byte col
    const int sw  = (sr & 7) << 4;     // staging swizzle

    int4 pk0, pk1, pv0, pv1;

    // prologue: stage tile 0 into buf 0; mask flag for tile 0 in registers
    pk0 = *(const int4*)(Kbh + (size_t)sr * 64 + (tid & 7) * 8);
    pk1 = *(const int4*)(Kbh + (size_t)(sr + 32) * 64 + (tid & 7) * 8);
    pv0 = *(const int4*)(Vbh + (size_t)sr * 2048 + (tid & 7) * 8);
    pv1 = *(const int4*)(Vbh + (size_t)(sr + 32) * 2048 + (tid & 7) * 8);
    int mcur = mrow[lane];
    *(int4*)(KsB0 + sr * 128 + (scb ^ sw)) = pk0;
    *(int4*)(KsB0 + (sr + 32) * 128 + (scb ^ sw)) = pk1;
    *(int4*)(VsB0 + sr * 128 + (scb ^ sw)) = pv0;
    *(int4*)(VsB0 + (sr + 32) * 128 + (scb ^ sw)) = pv1;
    __syncthreads();

    for (int t = 0; t < 32; ++t) {
        const int cur = t & 1, nxt = cur ^ 1;
        char* KsB = KsB0 + cur * 8192;
        char* VsB = VsB0 + cur * 8192;
        int mnxt = 1;
        // issue next tile's global loads early (latency hides under compute)
        if (t < 31) {
            int kvn = (t + 1) * 64;
            pk0 = *(const int4*)(Kbh + (size_t)(kvn + sr) * 64 + (tid & 7) * 8);
            pk1 = *(const int4*)(Kbh + (size_t)(kvn + sr + 32) * 64 + (tid & 7) * 8);
            pv0 = *(const int4*)(Vbh + (size_t)sr * 2048 + kvn + (tid & 7) * 8);
            pv1 = *(const int4*)(Vbh + (size_t)(sr + 32) * 2048 + kvn + (tid & 7) * 8);
            mnxt = mrow[kvn + lane];
        }

        // S = K Q : s[fi][kb][r] = S[k=kb*16+g*4+r][q=qw+fi*16+ql]
        f32x4 s[2][4];
        __builtin_amdgcn_s_setprio(1);
        #pragma unroll
        for (int kb = 0; kb < 4; kb++) {
            int row = kb * 16 + ql;
            int swz = (row & 7) << 4;
            bf16x8 kf0 = *(const bf16x8*)(KsB + row * 128 + ((g * 16) ^ swz));
            bf16x8 kf1 = *(const bf16x8*)(KsB + row * 128 + ((64 + g * 16) ^ swz));
            #pragma unroll
            for (int fi = 0; fi < 2; fi++) {
                f32x4 a = __builtin_amdgcn_mfma_f32_16x16x32_bf16(kf0, qf[fi][0], kZero, 0, 0, 0);
                a = __builtin_amdgcn_mfma_f32_16x16x32_bf16(kf1, qf[fi][1], a, 0, 0, 0);
                s[fi][kb] = a;
            }
        }
        __builtin_amdgcn_s_setprio(0);

        // mask (rare path; flag computed per-wave from registers)
        if (__ballot(mcur == 0) != 0ull) {
            #pragma unroll
            for (int kb = 0; kb < 4; kb++) {
                int4 mi = *(const int4*)&mrow[t * 64 + kb * 16 + g * 4];
                f32x4 mv;
                mv[0] = mi.x ? 0.f : -1e30f;
                mv[1] = mi.y ? 0.f : -1e30f;
                mv[2] = mi.z ? 0.f : -1e30f;
                mv[3] = mi.w ? 0.f : -1e30f;
                #pragma unroll
                for (int fi = 0; fi < 2; fi++)
                    #pragma unroll
                    for (int r = 0; r < 4; r++) s[fi][kb][r] += mv[r];
            }
        }

        // softmax-lite: p = exp2(s); per-fi P bounce via 2KB/wave buffer
        bf16x8 pf[2][2];
        #pragma unroll
        for (int fi = 0; fi < 2; fi++) {
            float ts[4];
            #pragma unroll
            for (int kb = 0; kb < 4; kb++) {
                float p0 = EXP2(s[fi][kb][0]);
                float p1 = EXP2(s[fi][kb][1]);
                float p2 = EXP2(s[fi][kb][2]);
                float p3 = EXP2(s[fi][kb][3]);
                ts[kb] = (p0 + p1) + (p2 + p3);
                bf16x4 pb;
                pb[0] = (__bf16)p0; pb[1] = (__bf16)p1;
                pb[2] = (__bf16)p2; pb[3] = (__bf16)p3;
                *(bf16x4*)(PlB + pwoff[kb]) = pb;
            }
            lrow[fi] += (ts[0] + ts[1]) + (ts[2] + ts[3]);
            #pragma unroll
            for (int ks = 0; ks < 2; ks++)
                pf[fi][ks] = *(const bf16x8*)(PlB + proff[ks]);
        }
        // O += V^T-as-A * P-as-B
        __builtin_amdgcn_s_setprio(1);
        #pragma unroll
        for (int dt = 0; dt < 4; dt++) {
            int row = dt * 16 + ql;
            int swz = (row & 7) << 4;
            bf16x8 vf0 = *(const bf16x8*)(VsB + row * 128 + ((g * 16) ^ swz));
            bf16x8 vf1 = *(const bf16x8*)(VsB + row * 128 + ((64 + g * 16) ^ swz));
            #pragma unroll
            for (int fi = 0; fi < 2; fi++) {
                oacc[fi][dt] = __builtin_amdgcn_mfma_f32_16x16x32_bf16(vf0, pf[fi][0], oacc[fi][dt], 0, 0, 0);
                oacc[fi][dt] = __builtin_amdgcn_mfma_f32_16x16x32_bf16(vf1, pf[fi][1], oacc[fi][dt], 0, 0, 0);
            }
        }
        __builtin_amdgcn_s_setprio(0);

        // write next tile into the other buffer, then single barrier
        if (t < 31) {
            char* KsN = KsB0 + nxt * 8192;
            char* VsN = VsB0 + nxt * 8192;
            *(int4*)(KsN + sr * 128 + (scb ^ sw)) = pk0;
            *(int4*)(KsN + (sr + 32) * 128 + (scb ^ sw)) = pk1;
            *(int4*)(VsN + sr * 128 + (scb ^ sw)) = pv0;
            *(int4*)(VsN + (sr + 32) * 128 + (scb ^ sw)) = pv1;
        }
        mcur = mnxt;
        __syncthreads();
    }

    // epilogue: finish row-sums (reduce over g), normalize, bounce via LDS
    #pragma unroll
    for (int fi = 0; fi < 2; fi++) {
        lrow[fi] += __shfl_xor(lrow[fi], 16, 64);
        lrow[fi] += __shfl_xor(lrow[fi], 32, 64);
        float inv = 1.f / lrow[fi];
        #pragma unroll
        for (int dt = 0; dt < 4; dt++) {
            bf16x4 ob;
            ob[0] = (__bf16)(oacc[fi][dt][0] * inv);
            ob[1] = (__bf16)(oacc[fi][dt][1] * inv);
            ob[2] = (__bf16)(oacc[fi][dt][2] * inv);
            ob[3] = (__bf16)(oacc[fi][dt][3] * inv);
            *(bf16x4*)(PlB + ql * 128 + ((dt * 32 + g * 8) ^ ((ql & 7) << 4))) = ob;
        }
        int rr = lane >> 2;
        int q = qw + fi * 16 + rr;
        #pragma unroll
        for (int pass = 0; pass < 2; pass++) {
            int cc = (lane & 3) + pass * 4;
            int4 val = *(const int4*)(PlB + rr * 128 + ((cc * 16) ^ ((rr & 7) << 4)));
            *(int4*)&O[((size_t)(b * 2048 + q)) * 1024 + h * 64 + cc * 8] = val;
        }
    }
}

// ---------------------------------------------------------------------------
// LayerNorm over last dim (1024), row per block, f32 in/out
// ---------------------------------------------------------------------------
__global__ __launch_bounds__(256) void ln_k(
    const float* __restrict__ X, const float* __restrict__ gamma,
    const float* __restrict__ beta, float* __restrict__ out)
{
    const int row = blockIdx.x, tid = threadIdx.x;
    float4 v = ((const float4*)(X + (size_t)row * 1024))[tid];
    float s = v.x + v.y + v.z + v.w;
    float s2 = v.x * v.x + v.y * v.y + v.z * v.z + v.w * v.w;
    #pragma unroll
    for (int off = 1; off < 64; off <<= 1) {
        s  += __shfl_xor(s, off, 64);
        s2 += __shfl_xor(s2, off, 64);
    }
    __shared__ float ss[4], ss2[4];
    int wid = tid >> 6;
    if ((tid & 63) == 0) { ss[wid] = s; ss2[wid] = s2; }
    __syncthreads();
    s = ss[0] + ss[1] + ss[2] + ss[3];
    s2 = ss2[0] + ss2[1] + ss2[2] + ss2[3];
    float mean = s * (1.f / 1024.f);
    float var = s2 * (1.f / 1024.f) - mean * mean;
    float rstd = rsqrtf(var + 1e-5f);
    float4 g = ((const float4*)gamma)[tid];
    float4 be = ((const float4*)beta)[tid];
    float4 o;
    o.x = (v.x - mean) * rstd * g.x + be.x;
    o.y = (v.y - mean) * rstd * g.y + be.y;
    o.z = (v.z - mean) * rstd * g.z + be.z;
    o.w = (v.w - mean) * rstd * g.w + be.w;
    ((float4*)(out + (size_t)row * 1024))[tid] = o;
}

// ---------------------------------------------------------------------------
extern "C" void kernel_launch(void* const* d_in, const int* in_sizes, int n_in,
                              void* d_out, int out_size, void* d_ws, size_t ws_size,
                              hipStream_t stream)
{
    const float* queries = (const float*)d_in[0];
    const float* keys    = (const float*)d_in[1];
    const float* values  = (const float*)d_in[2];
    const int*   mask    = (const int*)d_in[3];
    const float* Wq = (const float*)d_in[4];
    const float* bq = (const float*)d_in[5];
    const float* Wk = (const float*)d_in[6];
    const float* bk = (const float*)d_in[7];
    const float* Wv = (const float*)d_in[8];
    const float* bv = (const float*)d_in[9];
    const float* Wo = (const float*)d_in[10];
    const float* bo = (const float*)d_in[11];
    const float* gamma = (const float*)d_in[12];
    const float* beta  = (const float*)d_in[13];

    u16* ws = (u16*)d_ws;
    u16* Wt = ws;                       // 4 x 1048576 u16 (8 MB)
    u16* Qp = ws + 4 * 1048576;         // 8388608 u16 each
    u16* Kp = Qp + 8388608;
    u16* Vt = Kp + 8388608;
    u16* O  = Vt + 8388608;
    float* X = (float*)Qp;              // alias: Qp+Kp dead after attention

    // Q pre-scale folds 1/sqrt(64) * log2(e) so softmax runs in exp2 domain
    const float qscale = 0.125f * 1.44269504088896f;

    transpose4<<<dim3(32, 32, 4), 256, 0, stream>>>(Wq, Wk, Wv, Wo, Wt);
    gemm_bt<0, true ><<<dim3(64, 8), 256, 0, stream>>>(queries, Wt,           bq, nullptr, Qp, qscale);
    gemm_bt<0, true ><<<dim3(64, 8), 256, 0, stream>>>(keys,    Wt + 1048576, bk, nullptr, Kp, 1.0f);
    gemm_bt<1, true ><<<dim3(64, 8), 256, 0, stream>>>(values,  Wt + 2097152, bv, nullptr, Vt, 1.0f);
    attn_k<<<dim3(1024), 256, 0, stream>>>(Qp, Kp, Vt, mask, O);
    gemm_bt<2, false><<<dim3(64, 8), 256, 0, stream>>>(O, Wt + 3145728, bo, queries, X, 1.0f);
    ln_k<<<8192, 256, 0, stream>>>(X, gamma, beta, (float*)d_out);
}

// Round 7
// 242.200 us; speedup vs baseline: 1.2860x; 1.2860x over previous
//
#include <hip/hip_runtime.h>

typedef __bf16 bf16x8 __attribute__((ext_vector_type(8)));
typedef __bf16 bf16x4 __attribute__((ext_vector_type(4)));
typedef float f32x4 __attribute__((ext_vector_type(4)));
typedef unsigned short u16;

#if __has_builtin(__builtin_amdgcn_exp2f)
#define EXP2(x) __builtin_amdgcn_exp2f(x)
#else
#define EXP2(x) exp2f(x)
#endif

__device__ __forceinline__ float bf2f(u16 u){
    union { unsigned int i; float f; } x; x.i = ((unsigned int)u) << 16; return x.f;
}
__device__ __forceinline__ u16 f2bf(float f){
    union { float f; unsigned int i; } x; x.f = f;
    unsigned int r = x.i + 0x7fff + ((x.i >> 16) & 1);
    return (u16)(r >> 16);
}
__device__ __forceinline__ int4 cvt8(const float4 a, const float4 b){
    union { u16 h[8]; int4 v; } u;
    u.h[0] = f2bf(a.x); u.h[1] = f2bf(a.y); u.h[2] = f2bf(a.z); u.h[3] = f2bf(a.w);
    u.h[4] = f2bf(b.x); u.h[5] = f2bf(b.y); u.h[6] = f2bf(b.z); u.h[7] = f2bf(b.w);
    return u.v;
}

// ---------------------------------------------------------------------------
// Transpose 4 x [1024][1024] f32 weights -> bf16 Wt [N][K]
// ---------------------------------------------------------------------------
__global__ __launch_bounds__(256) void transpose4(
    const float* __restrict__ w0, const float* __restrict__ w1,
    const float* __restrict__ w2, const float* __restrict__ w3,
    u16* __restrict__ out)
{
    __shared__ float tile[32][33];
    int mat = blockIdx.z;
    const float* in = (mat == 0) ? w0 : (mat == 1) ? w1 : (mat == 2) ? w2 : w3;
    u16* o = out + (size_t)mat * 1048576;
    int bx = blockIdx.x * 32, by = blockIdx.y * 32;
    int tx = threadIdx.x & 31, ty = threadIdx.x >> 5; // 32 x 8
    #pragma unroll
    for (int i = 0; i < 32; i += 8)
        tile[ty + i][tx] = in[(size_t)(by + ty + i) * 1024 + bx + tx];
    __syncthreads();
    #pragma unroll
    for (int i = 0; i < 32; i += 8)
        o[(size_t)(bx + ty + i) * 1024 + by + tx] = f2bf(tile[tx][ty + i]);
}

// ---------------------------------------------------------------------------
// GEMM: C = A(8192x1024) * Bt(1024x1024)^T + bias, store per MODE
// AF32: A is f32 (converted to bf16 during LDS staging); else A is bf16.
// MODE 0: Q/K -> [b][h][q][d] bf16 (scaled)   MODE 1: V -> [b][h][d][q] bf16
// MODE 2: f32 row-major + f32 residual
// ---------------------------------------------------------------------------
template<int MODE, bool AF32>
__global__ __launch_bounds__(256) void gemm_bt(
    const void* __restrict__ Av, const u16* __restrict__ Bt,
    const float* __restrict__ bias, const float* __restrict__ resid,
    void* __restrict__ Cv, float scale)
{
    constexpr int K = 1024;
    __shared__ alignas(16) u16 As[2][128][32];
    __shared__ alignas(16) u16 Bs[2][128][32];
    const int tid = threadIdx.x;
    const int lane = tid & 63, wid = tid >> 6;
    const int wm = wid >> 1, wn = wid & 1;
    const int m0 = blockIdx.x * 128, n0 = blockIdx.y * 128;
    const int r0 = tid >> 2;            // 0..63
    const int kc = (tid & 3) * 8;       // 0,8,16,24
    const int fr = lane & 15, fk = (lane >> 4) * 8;

    const float* Af0 = (const float*)Av + (size_t)(m0 + r0) * K + kc;
    const float* Af1 = Af0 + (size_t)64 * K;
    const u16*   Ah0 = (const u16*)Av + (size_t)(m0 + r0) * K + kc;
    const u16*   Ah1 = Ah0 + (size_t)64 * K;
    const u16* Brow0 = Bt + (size_t)(n0 + r0) * K + kc;
    const u16* Brow1 = Brow0 + (size_t)64 * K;

    int4 pa0, pa1, pb0, pb1;
    if constexpr (AF32) {
        pa0 = cvt8(((const float4*)Af0)[0], ((const float4*)Af0)[1]);
        pa1 = cvt8(((const float4*)Af1)[0], ((const float4*)Af1)[1]);
    } else {
        pa0 = *(const int4*)(Ah0);
        pa1 = *(const int4*)(Ah1);
    }
    pb0 = *(const int4*)(Brow0);
    pb1 = *(const int4*)(Brow1);
    *(int4*)&As[0][r0][kc]      = pa0;
    *(int4*)&As[0][r0 + 64][kc] = pa1;
    *(int4*)&Bs[0][r0][kc]      = pb0;
    *(int4*)&Bs[0][r0 + 64][kc] = pb1;
    __syncthreads();

    f32x4 acc[4][4] = {};
    constexpr int NT = K / 32;
    for (int t = 0; t < NT; ++t) {
        int cur = t & 1, nxt = cur ^ 1;
        if (t + 1 < NT) {
            if constexpr (AF32) {
                pa0 = cvt8(((const float4*)(Af0 + (t + 1) * 32))[0],
                           ((const float4*)(Af0 + (t + 1) * 32))[1]);
                pa1 = cvt8(((const float4*)(Af1 + (t + 1) * 32))[0],
                           ((const float4*)(Af1 + (t + 1) * 32))[1]);
            } else {
                pa0 = *(const int4*)(Ah0 + (t + 1) * 32);
                pa1 = *(const int4*)(Ah1 + (t + 1) * 32);
            }
            pb0 = *(const int4*)(Brow0 + (t + 1) * 32);
            pb1 = *(const int4*)(Brow1 + (t + 1) * 32);
        }
        bf16x8 af[4], bfr[4];
        #pragma unroll
        for (int i = 0; i < 4; i++) {
            af[i]  = *(const bf16x8*)&As[cur][wm * 64 + i * 16 + fr][fk];
            bfr[i] = *(const bf16x8*)&Bs[cur][wn * 64 + i * 16 + fr][fk];
        }
        #pragma unroll
        for (int mi = 0; mi < 4; mi++)
            #pragma unroll
            for (int ni = 0; ni < 4; ni++)
                acc[mi][ni] = __builtin_amdgcn_mfma_f32_16x16x32_bf16(
                    af[mi], bfr[ni], acc[mi][ni], 0, 0, 0);
        if (t + 1 < NT) {
            *(int4*)&As[nxt][r0][kc]      = pa0;
            *(int4*)&As[nxt][r0 + 64][kc] = pa1;
            *(int4*)&Bs[nxt][r0][kc]      = pb0;
            *(int4*)&Bs[nxt][r0 + 64][kc] = pb1;
        }
        __syncthreads();
    }

    #pragma unroll
    for (int ni = 0; ni < 4; ni++) {
        int col = n0 + wn * 64 + ni * 16 + fr;
        float bcol = bias[col];
        #pragma unroll
        for (int mi = 0; mi < 4; mi++) {
            #pragma unroll
            for (int r = 0; r < 4; r++) {
                int m = m0 + wm * 64 + mi * 16 + (lane >> 4) * 4 + r;
                float val = acc[mi][ni][r] + bcol;
                if (MODE == 2) {
                    val += resid[(size_t)m * 1024 + col];
                    ((float*)Cv)[(size_t)m * 1024 + col] = val;
                } else {
                    val *= scale;
                    int b = m >> 11, q = m & 2047;
                    int h = col >> 6, d = col & 63;
                    size_t base = (size_t)(b * 16 + h) * 131072;
                    if (MODE == 0) ((u16*)Cv)[base + (size_t)q * 64 + d] = f2bf(val);
                    else           ((u16*)Cv)[base + (size_t)d * 2048 + q] = f2bf(val);
                }
            }
        }
    }
}

// ---------------------------------------------------------------------------
// Flash attention v5b: swapped QK^T, XOR-swizzled LDS, QBLK=128, exp2-domain
// softmax-lite, per-lane deferred row-sum, K/V double-buffer, setprio,
// XCD-bijective swizzle. LDS exactly 40960 B -> 4 blocks/CU; NO min-waves
// clause (R6's __launch_bounds__(256,4) capped VGPR to 64 and spilled:
// 289 MB scratch writes). Natural VGPR ~108 fits 4 waves/SIMD anyway.
// Qp/Kp [bh][2048][64] (Q pre-scaled by 1/8*log2e), Vt [bh][64][2048]
// -> O [b][q][h*64+d] bf16
// ---------------------------------------------------------------------------
__global__ __launch_bounds__(256) void attn_k(
    const u16* __restrict__ Qp, const u16* __restrict__ Kp,
    const u16* __restrict__ Vt, const int* __restrict__ mask,
    u16* __restrict__ O)
{
    __shared__ alignas(16) u16 Ks[2][64][64];   // [buf][kv][d], swizzled (16 KB)
    __shared__ alignas(16) u16 Vs[2][64][64];   // [buf][d][kv], swizzled (16 KB)
    __shared__ alignas(16) u16 Pl[4][16][64];   // per-wave 2KB P bounce (8 KB)

    // XCD-bijective swizzle: all 16 q-tiles of one bh share blockIdx%8 (same XCD)
    const int wg = blockIdx.x;                 // 0..1023
    const int xc = wg & 7;
    const int rm = wg >> 3;                    // 0..127
    const int qx = rm & 15;
    const int bh = (rm >> 4) * 8 + xc;         // bijective
    const int b = bh >> 4, h = bh & 15;
    const int q0 = qx * 128;
    const int tid = threadIdx.x, wid = tid >> 6, lane = tid & 63;
    const int ql = lane & 15, g = lane >> 4;
    const int qw = q0 + wid * 32;

    const u16* Qbh = Qp + (size_t)bh * 131072;
    const u16* Kbh = Kp + (size_t)bh * 131072;
    const u16* Vbh = Vt + (size_t)bh * 131072;
    const int* mrow = mask + b * 2048;

    char* KsB0 = (char*)Ks;
    char* VsB0 = (char*)Vs;
    char* PlB = (char*)Pl + wid * 2048;

    // Q fragments (B-operand layout): qf[fi][ks], q = qw + fi*16 + ql
    bf16x8 qf[2][2];
    #pragma unroll
    for (int fi = 0; fi < 2; fi++)
        #pragma unroll
        for (int ks = 0; ks < 2; ks++)
            qf[fi][ks] = *(const bf16x8*)&Qbh[(size_t)(qw + fi * 16 + ql) * 64 + ks * 32 + g * 8];

    f32x4 oacc[2][4] = {};
    float lrow[2] = {0.f, 0.f};               // per-lane partial row-sums
    const f32x4 kZero = {0.f, 0.f, 0.f, 0.f}; // persistent zero C operand

    // loop-invariant P LDS offsets (per-wave [16][64] buffer, row = ql)
    int pwoff[4], proff[2];
    #pragma unroll
    for (int kb = 0; kb < 4; kb++)
        pwoff[kb] = ql * 128 + ((kb * 32 + g * 8) ^ ((ql & 7) << 4));
    #pragma unroll
    for (int ks = 0; ks < 2; ks++)
        proff[ks] = ql * 128 + ((ks * 64 + g * 16) ^ ((ql & 7) << 4));

    const int sr  = tid >> 3;          // staging row 0..31 (x2)
    const int scb = (tid & 7) * 16;    // staging byte col
    const int sw  = (sr & 7) << 4;     // staging swizzle

    int4 pk0, pk1, pv0, pv1;

    // prologue: stage tile 0 into buf 0; mask flag for tile 0 in registers
    pk0 = *(const int4*)(Kbh + (size_t)sr * 64 + (tid & 7) * 8);
    pk1 = *(const int4*)(Kbh + (size_t)(sr + 32) * 64 + (tid & 7) * 8);
    pv0 = *(const int4*)(Vbh + (size_t)sr * 2048 + (tid & 7) * 8);
    pv1 = *(const int4*)(Vbh + (size_t)(sr + 32) * 2048 + (tid & 7) * 8);
    int mcur = mrow[lane];
    *(int4*)(KsB0 + sr * 128 + (scb ^ sw)) = pk0;
    *(int4*)(KsB0 + (sr + 32) * 128 + (scb ^ sw)) = pk1;
    *(int4*)(VsB0 + sr * 128 + (scb ^ sw)) = pv0;
    *(int4*)(VsB0 + (sr + 32) * 128 + (scb ^ sw)) = pv1;
    __syncthreads();

    for (int t = 0; t < 32; ++t) {
        const int cur = t & 1, nxt = cur ^ 1;
        char* KsB = KsB0 + cur * 8192;
        char* VsB = VsB0 + cur * 8192;
        int mnxt = 1;
        // issue next tile's global loads early (latency hides under compute)
        if (t < 31) {
            int kvn = (t + 1) * 64;
            pk0 = *(const int4*)(Kbh + (size_t)(kvn + sr) * 64 + (tid & 7) * 8);
            pk1 = *(const int4*)(Kbh + (size_t)(kvn + sr + 32) * 64 + (tid & 7) * 8);
            pv0 = *(const int4*)(Vbh + (size_t)sr * 2048 + kvn + (tid & 7) * 8);
            pv1 = *(const int4*)(Vbh + (size_t)(sr + 32) * 2048 + kvn + (tid & 7) * 8);
            mnxt = mrow[kvn + lane];
        }

        // S = K Q : s[fi][kb][r] = S[k=kb*16+g*4+r][q=qw+fi*16+ql]
        f32x4 s[2][4];
        __builtin_amdgcn_s_setprio(1);
        #pragma unroll
        for (int kb = 0; kb < 4; kb++) {
            int row = kb * 16 + ql;
            int swz = (row & 7) << 4;
            bf16x8 kf0 = *(const bf16x8*)(KsB + row * 128 + ((g * 16) ^ swz));
            bf16x8 kf1 = *(const bf16x8*)(KsB + row * 128 + ((64 + g * 16) ^ swz));
            #pragma unroll
            for (int fi = 0; fi < 2; fi++) {
                f32x4 a = __builtin_amdgcn_mfma_f32_16x16x32_bf16(kf0, qf[fi][0], kZero, 0, 0, 0);
                a = __builtin_amdgcn_mfma_f32_16x16x32_bf16(kf1, qf[fi][1], a, 0, 0, 0);
                s[fi][kb] = a;
            }
        }
        __builtin_amdgcn_s_setprio(0);

        // mask (rare path; flag computed per-wave from registers)
        if (__ballot(mcur == 0) != 0ull) {
            #pragma unroll
            for (int kb = 0; kb < 4; kb++) {
                int4 mi = *(const int4*)&mrow[t * 64 + kb * 16 + g * 4];
                f32x4 mv;
                mv[0] = mi.x ? 0.f : -1e30f;
                mv[1] = mi.y ? 0.f : -1e30f;
                mv[2] = mi.z ? 0.f : -1e30f;
                mv[3] = mi.w ? 0.f : -1e30f;
                #pragma unroll
                for (int fi = 0; fi < 2; fi++)
                    #pragma unroll
                    for (int r = 0; r < 4; r++) s[fi][kb][r] += mv[r];
            }
        }

        // softmax-lite: p = exp2(s); per-fi P bounce via 2KB/wave buffer
        bf16x8 pf[2][2];
        #pragma unroll
        for (int fi = 0; fi < 2; fi++) {
            float ts[4];
            #pragma unroll
            for (int kb = 0; kb < 4; kb++) {
                float p0 = EXP2(s[fi][kb][0]);
                float p1 = EXP2(s[fi][kb][1]);
                float p2 = EXP2(s[fi][kb][2]);
                float p3 = EXP2(s[fi][kb][3]);
                ts[kb] = (p0 + p1) + (p2 + p3);
                bf16x4 pb;
                pb[0] = (__bf16)p0; pb[1] = (__bf16)p1;
                pb[2] = (__bf16)p2; pb[3] = (__bf16)p3;
                *(bf16x4*)(PlB + pwoff[kb]) = pb;
            }
            lrow[fi] += (ts[0] + ts[1]) + (ts[2] + ts[3]);
            #pragma unroll
            for (int ks = 0; ks < 2; ks++)
                pf[fi][ks] = *(const bf16x8*)(PlB + proff[ks]);
        }
        // O += V^T-as-A * P-as-B
        __builtin_amdgcn_s_setprio(1);
        #pragma unroll
        for (int dt = 0; dt < 4; dt++) {
            int row = dt * 16 + ql;
            int swz = (row & 7) << 4;
            bf16x8 vf0 = *(const bf16x8*)(VsB + row * 128 + ((g * 16) ^ swz));
            bf16x8 vf1 = *(const bf16x8*)(VsB + row * 128 + ((64 + g * 16) ^ swz));
            #pragma unroll
            for (int fi = 0; fi < 2; fi++) {
                oacc[fi][dt] = __builtin_amdgcn_mfma_f32_16x16x32_bf16(vf0, pf[fi][0], oacc[fi][dt], 0, 0, 0);
                oacc[fi][dt] = __builtin_amdgcn_mfma_f32_16x16x32_bf16(vf1, pf[fi][1], oacc[fi][dt], 0, 0, 0);
            }
        }
        __builtin_amdgcn_s_setprio(0);

        // write next tile into the other buffer, then single barrier
        if (t < 31) {
            char* KsN = KsB0 + nxt * 8192;
            char* VsN = VsB0 + nxt * 8192;
            *(int4*)(KsN + sr * 128 + (scb ^ sw)) = pk0;
            *(int4*)(KsN + (sr + 32) * 128 + (scb ^ sw)) = pk1;
            *(int4*)(VsN + sr * 128 + (scb ^ sw)) = pv0;
            *(int4*)(VsN + (sr + 32) * 128 + (scb ^ sw)) = pv1;
        }
        mcur = mnxt;
        __syncthreads();
    }

    // epilogue: finish row-sums (reduce over g), normalize, bounce via LDS
    #pragma unroll
    for (int fi = 0; fi < 2; fi++) {
        lrow[fi] += __shfl_xor(lrow[fi], 16, 64);
        lrow[fi] += __shfl_xor(lrow[fi], 32, 64);
        float inv = 1.f / lrow[fi];
        #pragma unroll
        for (int dt = 0; dt < 4; dt++) {
            bf16x4 ob;
            ob[0] = (__bf16)(oacc[fi][dt][0] * inv);
            ob[1] = (__bf16)(oacc[fi][dt][1] * inv);
            ob[2] = (__bf16)(oacc[fi][dt][2] * inv);
            ob[3] = (__bf16)(oacc[fi][dt][3] * inv);
            *(bf16x4*)(PlB + ql * 128 + ((dt * 32 + g * 8) ^ ((ql & 7) << 4))) = ob;
        }
        int rr = lane >> 2;
        int q = qw + fi * 16 + rr;
        #pragma unroll
        for (int pass = 0; pass < 2; pass++) {
            int cc = (lane & 3) + pass * 4;
            int4 val = *(const int4*)(PlB + rr * 128 + ((cc * 16) ^ ((rr & 7) << 4)));
            *(int4*)&O[((size_t)(b * 2048 + q)) * 1024 + h * 64 + cc * 8] = val;
        }
    }
}

// ---------------------------------------------------------------------------
// LayerNorm over last dim (1024), row per block, f32 in/out
// ---------------------------------------------------------------------------
__global__ __launch_bounds__(256) void ln_k(
    const float* __restrict__ X, const float* __restrict__ gamma,
    const float* __restrict__ beta, float* __restrict__ out)
{
    const int row = blockIdx.x, tid = threadIdx.x;
    float4 v = ((const float4*)(X + (size_t)row * 1024))[tid];
    float s = v.x + v.y + v.z + v.w;
    float s2 = v.x * v.x + v.y * v.y + v.z * v.z + v.w * v.w;
    #pragma unroll
    for (int off = 1; off < 64; off <<= 1) {
        s  += __shfl_xor(s, off, 64);
        s2 += __shfl_xor(s2, off, 64);
    }
    __shared__ float ss[4], ss2[4];
    int wid = tid >> 6;
    if ((tid & 63) == 0) { ss[wid] = s; ss2[wid] = s2; }
    __syncthreads();
    s = ss[0] + ss[1] + ss[2] + ss[3];
    s2 = ss2[0] + ss2[1] + ss2[2] + ss2[3];
    float mean = s * (1.f / 1024.f);
    float var = s2 * (1.f / 1024.f) - mean * mean;
    float rstd = rsqrtf(var + 1e-5f);
    float4 g = ((const float4*)gamma)[tid];
    float4 be = ((const float4*)beta)[tid];
    float4 o;
    o.x = (v.x - mean) * rstd * g.x + be.x;
    o.y = (v.y - mean) * rstd * g.y + be.y;
    o.z = (v.z - mean) * rstd * g.z + be.z;
    o.w = (v.w - mean) * rstd * g.w + be.w;
    ((float4*)(out + (size_t)row * 1024))[tid] = o;
}

// ---------------------------------------------------------------------------
extern "C" void kernel_launch(void* const* d_in, const int* in_sizes, int n_in,
                              void* d_out, int out_size, void* d_ws, size_t ws_size,
                              hipStream_t stream)
{
    const float* queries = (const float*)d_in[0];
    const float* keys    = (const float*)d_in[1];
    const float* values  = (const float*)d_in[2];
    const int*   mask    = (const int*)d_in[3];
    const float* Wq = (const float*)d_in[4];
    const float* bq = (const float*)d_in[5];
    const float* Wk = (const float*)d_in[6];
    const float* bk = (const float*)d_in[7];
    const float* Wv = (const float*)d_in[8];
    const float* bv = (const float*)d_in[9];
    const float* Wo = (const float*)d_in[10];
    const float* bo = (const float*)d_in[11];
    const float* gamma = (const float*)d_in[12];
    const float* beta  = (const float*)d_in[13];

    u16* ws = (u16*)d_ws;
    u16* Wt = ws;                       // 4 x 1048576 u16 (8 MB)
    u16* Qp = ws + 4 * 1048576;         // 8388608 u16 each
    u16* Kp = Qp + 8388608;
    u16* Vt = Kp + 8388608;
    u16* O  = Vt + 8388608;
    float* X = (float*)Qp;              // alias: Qp+Kp dead after attention

    // Q pre-scale folds 1/sqrt(64) * log2(e) so softmax runs in exp2 domain
    const float qscale = 0.125f * 1.44269504088896f;

    transpose4<<<dim3(32, 32, 4), 256, 0, stream>>>(Wq, Wk, Wv, Wo, Wt);
    gemm_bt<0, true ><<<dim3(64, 8), 256, 0, stream>>>(queries, Wt,           bq, nullptr, Qp, qscale);
    gemm_bt<0, true ><<<dim3(64, 8), 256, 0, stream>>>(keys,    Wt + 1048576, bk, nullptr, Kp, 1.0f);
    gemm_bt<1, true ><<<dim3(64, 8), 256, 0, stream>>>(values,  Wt + 2097152, bv, nullptr, Vt, 1.0f);
    attn_k<<<dim3(1024), 256, 0, stream>>>(Qp, Kp, Vt, mask, O);
    gemm_bt<2, false><<<dim3(64, 8), 256, 0, stream>>>(O, Wt + 3145728, bo, queries, X, 1.0f);
    ln_k<<<8192, 256, 0, stream>>>(X, gamma, beta, (float*)d_out);
}

// Round 8
// 240.010 us; speedup vs baseline: 1.2978x; 1.0091x over previous
//
#include <hip/hip_runtime.h>

typedef __bf16 bf16x8 __attribute__((ext_vector_type(8)));
typedef __bf16 bf16x4 __attribute__((ext_vector_type(4)));
typedef float f32x4 __attribute__((ext_vector_type(4)));
typedef unsigned short u16;

#if __has_builtin(__builtin_amdgcn_exp2f)
#define EXP2(x) __builtin_amdgcn_exp2f(x)
#else
#define EXP2(x) exp2f(x)
#endif

__device__ __forceinline__ float bf2f(u16 u){
    union { unsigned int i; float f; } x; x.i = ((unsigned int)u) << 16; return x.f;
}
__device__ __forceinline__ u16 f2bf(float f){
    union { float f; unsigned int i; } x; x.f = f;
    unsigned int r = x.i + 0x7fff + ((x.i >> 16) & 1);
    return (u16)(r >> 16);
}
__device__ __forceinline__ int4 cvt8(const float4 a, const float4 b){
    union { u16 h[8]; int4 v; } u;
    u.h[0] = f2bf(a.x); u.h[1] = f2bf(a.y); u.h[2] = f2bf(a.z); u.h[3] = f2bf(a.w);
    u.h[4] = f2bf(b.x); u.h[5] = f2bf(b.y); u.h[6] = f2bf(b.z); u.h[7] = f2bf(b.w);
    return u.v;
}
// async global->LDS, 16B per lane; dest is wave-uniform base + lane*16 (linear)
__device__ __forceinline__ void gload_lds16(const void* g, void* l){
    __builtin_amdgcn_global_load_lds(
        (const __attribute__((address_space(1))) unsigned int*)g,
        (__attribute__((address_space(3))) unsigned int*)l, 16, 0, 0);
}

// ---------------------------------------------------------------------------
// Transpose 4 x [1024][1024] f32 weights -> bf16 Wt [N][K]
// ---------------------------------------------------------------------------
__global__ __launch_bounds__(256) void transpose4(
    const float* __restrict__ w0, const float* __restrict__ w1,
    const float* __restrict__ w2, const float* __restrict__ w3,
    u16* __restrict__ out)
{
    __shared__ float tile[32][33];
    int mat = blockIdx.z;
    const float* in = (mat == 0) ? w0 : (mat == 1) ? w1 : (mat == 2) ? w2 : w3;
    u16* o = out + (size_t)mat * 1048576;
    int bx = blockIdx.x * 32, by = blockIdx.y * 32;
    int tx = threadIdx.x & 31, ty = threadIdx.x >> 5; // 32 x 8
    #pragma unroll
    for (int i = 0; i < 32; i += 8)
        tile[ty + i][tx] = in[(size_t)(by + ty + i) * 1024 + bx + tx];
    __syncthreads();
    #pragma unroll
    for (int i = 0; i < 32; i += 8)
        o[(size_t)(bx + ty + i) * 1024 + by + tx] = f2bf(tile[tx][ty + i]);
}

// ---------------------------------------------------------------------------
// GEMM: C = A(8192x1024) * Bt(1024x1024)^T + bias, store per MODE
// AF32: A is f32 (converted to bf16 during LDS staging); else A is bf16.
// MODE 0: Q/K -> [b][h][q][d] bf16 (scaled)   MODE 1: V -> [b][h][d][q] bf16
// MODE 2: bf16 row-major + f32 residual
// ---------------------------------------------------------------------------
template<int MODE, bool AF32>
__global__ __launch_bounds__(256) void gemm_bt(
    const void* __restrict__ Av, const u16* __restrict__ Bt,
    const float* __restrict__ bias, const float* __restrict__ resid,
    void* __restrict__ Cv, float scale)
{
    constexpr int K = 1024;
    __shared__ alignas(16) u16 As[2][128][32];
    __shared__ alignas(16) u16 Bs[2][128][32];
    const int tid = threadIdx.x;
    const int lane = tid & 63, wid = tid >> 6;
    const int wm = wid >> 1, wn = wid & 1;
    const int m0 = blockIdx.x * 128, n0 = blockIdx.y * 128;
    const int r0 = tid >> 2;            // 0..63
    const int kc = (tid & 3) * 8;       // 0,8,16,24
    const int fr = lane & 15, fk = (lane >> 4) * 8;

    const float* Af0 = (const float*)Av + (size_t)(m0 + r0) * K + kc;
    const float* Af1 = Af0 + (size_t)64 * K;
    const u16*   Ah0 = (const u16*)Av + (size_t)(m0 + r0) * K + kc;
    const u16*   Ah1 = Ah0 + (size_t)64 * K;
    const u16* Brow0 = Bt + (size_t)(n0 + r0) * K + kc;
    const u16* Brow1 = Brow0 + (size_t)64 * K;

    int4 pa0, pa1, pb0, pb1;
    if constexpr (AF32) {
        pa0 = cvt8(((const float4*)Af0)[0], ((const float4*)Af0)[1]);
        pa1 = cvt8(((const float4*)Af1)[0], ((const float4*)Af1)[1]);
    } else {
        pa0 = *(const int4*)(Ah0);
        pa1 = *(const int4*)(Ah1);
    }
    pb0 = *(const int4*)(Brow0);
    pb1 = *(const int4*)(Brow1);
    *(int4*)&As[0][r0][kc]      = pa0;
    *(int4*)&As[0][r0 + 64][kc] = pa1;
    *(int4*)&Bs[0][r0][kc]      = pb0;
    *(int4*)&Bs[0][r0 + 64][kc] = pb1;
    __syncthreads();

    f32x4 acc[4][4] = {};
    constexpr int NT = K / 32;
    for (int t = 0; t < NT; ++t) {
        int cur = t & 1, nxt = cur ^ 1;
        if (t + 1 < NT) {
            if constexpr (AF32) {
                pa0 = cvt8(((const float4*)(Af0 + (t + 1) * 32))[0],
                           ((const float4*)(Af0 + (t + 1) * 32))[1]);
                pa1 = cvt8(((const float4*)(Af1 + (t + 1) * 32))[0],
                           ((const float4*)(Af1 + (t + 1) * 32))[1]);
            } else {
                pa0 = *(const int4*)(Ah0 + (t + 1) * 32);
                pa1 = *(const int4*)(Ah1 + (t + 1) * 32);
            }
            pb0 = *(const int4*)(Brow0 + (t + 1) * 32);
            pb1 = *(const int4*)(Brow1 + (t + 1) * 32);
        }
        bf16x8 af[4], bfr[4];
        #pragma unroll
        for (int i = 0; i < 4; i++) {
            af[i]  = *(const bf16x8*)&As[cur][wm * 64 + i * 16 + fr][fk];
            bfr[i] = *(const bf16x8*)&Bs[cur][wn * 64 + i * 16 + fr][fk];
        }
        #pragma unroll
        for (int mi = 0; mi < 4; mi++)
            #pragma unroll
            for (int ni = 0; ni < 4; ni++)
                acc[mi][ni] = __builtin_amdgcn_mfma_f32_16x16x32_bf16(
                    af[mi], bfr[ni], acc[mi][ni], 0, 0, 0);
        if (t + 1 < NT) {
            *(int4*)&As[nxt][r0][kc]      = pa0;
            *(int4*)&As[nxt][r0 + 64][kc] = pa1;
            *(int4*)&Bs[nxt][r0][kc]      = pb0;
            *(int4*)&Bs[nxt][r0 + 64][kc] = pb1;
        }
        __syncthreads();
    }

    #pragma unroll
    for (int ni = 0; ni < 4; ni++) {
        int col = n0 + wn * 64 + ni * 16 + fr;
        float bcol = bias[col];
        #pragma unroll
        for (int mi = 0; mi < 4; mi++) {
            #pragma unroll
            for (int r = 0; r < 4; r++) {
                int m = m0 + wm * 64 + mi * 16 + (lane >> 4) * 4 + r;
                float val = acc[mi][ni][r] + bcol;
                if (MODE == 2) {
                    val += resid[(size_t)m * 1024 + col];
                    ((u16*)Cv)[(size_t)m * 1024 + col] = f2bf(val);
                } else {
                    val *= scale;
                    int b = m >> 11, q = m & 2047;
                    int h = col >> 6, d = col & 63;
                    size_t base = (size_t)(b * 16 + h) * 131072;
                    if (MODE == 0) ((u16*)Cv)[base + (size_t)q * 64 + d] = f2bf(val);
                    else           ((u16*)Cv)[base + (size_t)d * 2048 + q] = f2bf(val);
                }
            }
        }
    }
}

// ---------------------------------------------------------------------------
// Flash attention v6: swapped QK^T, XOR-swizzled LDS, QBLK=128, exp2-domain
// softmax-lite, per-lane deferred row-sum, setprio, XCD-bijective swizzle.
// K/V staging now via global_load_lds (linear LDS dest + pre-swizzled global
// source = rule-21-correct): kills 16 staging VGPRs + staging VALU so more
// waves fit (register-bound occupancy was the R7 limiter).
// Qp/Kp [bh][2048][64] (Q pre-scaled by 1/8*log2e), Vt [bh][64][2048]
// -> O [b][q][h*64+d] bf16
// ---------------------------------------------------------------------------
__global__ __launch_bounds__(256) void attn_k(
    const u16* __restrict__ Qp, const u16* __restrict__ Kp,
    const u16* __restrict__ Vt, const int* __restrict__ mask,
    u16* __restrict__ O)
{
    __shared__ alignas(16) u16 Ks[2][64][64];   // [buf][kv][d], swizzled (16 KB)
    __shared__ alignas(16) u16 Vs[2][64][64];   // [buf][d][kv], swizzled (16 KB)
    __shared__ alignas(16) u16 Pl[4][16][64];   // per-wave 2KB P bounce (8 KB)

    // XCD-bijective swizzle: all 16 q-tiles of one bh share blockIdx%8 (same XCD)
    const int wg = blockIdx.x;                 // 0..1023
    const int xc = wg & 7;
    const int rm = wg >> 3;                    // 0..127
    const int qx = rm & 15;
    const int bh = (rm >> 4) * 8 + xc;         // bijective
    const int b = bh >> 4, h = bh & 15;
    const int q0 = qx * 128;
    const int tid = threadIdx.x, wid = tid >> 6, lane = tid & 63;
    const int ql = lane & 15, g = lane >> 4;
    const int qw = q0 + wid * 32;

    const u16* Qbh = Qp + (size_t)bh * 131072;
    const u16* Kbh = Kp + (size_t)bh * 131072;
    const u16* Vbh = Vt + (size_t)bh * 131072;
    const int* mrow = mask + b * 2048;

    char* KsB0 = (char*)Ks;
    char* VsB0 = (char*)Vs;
    char* PlB = (char*)Pl + wid * 2048;

    // Q fragments (B-operand layout): qf[fi][ks], q = qw + fi*16 + ql
    bf16x8 qf[2][2];
    #pragma unroll
    for (int fi = 0; fi < 2; fi++)
        #pragma unroll
        for (int ks = 0; ks < 2; ks++)
            qf[fi][ks] = *(const bf16x8*)&Qbh[(size_t)(qw + fi * 16 + ql) * 64 + ks * 32 + g * 8];

    f32x4 oacc[2][4] = {};
    float lrow[2] = {0.f, 0.f};               // per-lane partial row-sums
    const f32x4 kZero = {0.f, 0.f, 0.f, 0.f}; // persistent zero C operand

    // loop-invariant P LDS offsets (per-wave [16][64] buffer, row = ql)
    int pwoff[4], proff[2];
    #pragma unroll
    for (int kb = 0; kb < 4; kb++)
        pwoff[kb] = ql * 128 + ((kb * 32 + g * 8) ^ ((ql & 7) << 4));
    #pragma unroll
    for (int ks = 0; ks < 2; ks++)
        proff[ks] = ql * 128 + ((ks * 64 + g * 16) ^ ((ql & 7) << 4));

    // global_load_lds staging geometry: wave wid owns tile rows [wid*16, wid*16+16)
    // lane l -> dest byte = base + l*16  (row = rb + i*8 + (l>>3), chunk = l&7)
    // source chunk pre-XORed so that swizzled reads see the identity layout.
    const int lrow8 = lane >> 3;                       // 0..7
    const int coff  = ((lane & 7) ^ lrow8) << 4;       // swizzled source byte chunk
    const int rb    = wid * 16;                        // wave's row base in tile

    // stage tile tt's K and V into buffer buf (4 x 1KB async copies per wave)
    auto stage = [&](int buf, int tt) {
        const size_t kv0 = (size_t)tt * 64;
        #pragma unroll
        for (int i = 0; i < 2; i++) {
            const int rt = rb + i * 8;                 // uniform row base
            gload_lds16((const char*)Kbh + (kv0 + rt + lrow8) * 128 + coff,
                        KsB0 + buf * 8192 + rt * 128);
            gload_lds16((const char*)Vbh + (size_t)(rt + lrow8) * 4096 + kv0 * 2 + coff,
                        VsB0 + buf * 8192 + rt * 128);
        }
    };

    // prologue: stage tile 0 into buf 0 (barrier below drains vmcnt)
    stage(0, 0);
    int mcur = mrow[lane];
    __syncthreads();

    for (int t = 0; t < 32; ++t) {
        const int cur = t & 1, nxt = cur ^ 1;
        char* KsB = KsB0 + cur * 8192;
        char* VsB = VsB0 + cur * 8192;
        int mnxt = 1;
        // issue next tile's async loads now; they fly under this tile's compute.
        // (buffer nxt was last read at t-1, before the barrier that ended it)
        if (t < 31) {
            stage(nxt, t + 1);
            mnxt = mrow[(t + 1) * 64 + lane];
        }

        // S = K Q : s[fi][kb][r] = S[k=kb*16+g*4+r][q=qw+fi*16+ql]
        f32x4 s[2][4];
        __builtin_amdgcn_s_setprio(1);
        #pragma unroll
        for (int kb = 0; kb < 4; kb++) {
            int row = kb * 16 + ql;
            int swz = (row & 7) << 4;
            bf16x8 kf0 = *(const bf16x8*)(KsB + row * 128 + ((g * 16) ^ swz));
            bf16x8 kf1 = *(const bf16x8*)(KsB + row * 128 + ((64 + g * 16) ^ swz));
            #pragma unroll
            for (int fi = 0; fi < 2; fi++) {
                f32x4 a = __builtin_amdgcn_mfma_f32_16x16x32_bf16(kf0, qf[fi][0], kZero, 0, 0, 0);
                a = __builtin_amdgcn_mfma_f32_16x16x32_bf16(kf1, qf[fi][1], a, 0, 0, 0);
                s[fi][kb] = a;
            }
        }
        __builtin_amdgcn_s_setprio(0);

        // mask (rare path; flag computed per-wave from registers)
        if (__ballot(mcur == 0) != 0ull) {
            #pragma unroll
            for (int kb = 0; kb < 4; kb++) {
                int4 mi = *(const int4*)&mrow[t * 64 + kb * 16 + g * 4];
                f32x4 mv;
                mv[0] = mi.x ? 0.f : -1e30f;
                mv[1] = mi.y ? 0.f : -1e30f;
                mv[2] = mi.z ? 0.f : -1e30f;
                mv[3] = mi.w ? 0.f : -1e30f;
                #pragma unroll
                for (int fi = 0; fi < 2; fi++)
                    #pragma unroll
                    for (int r = 0; r < 4; r++) s[fi][kb][r] += mv[r];
            }
        }

        // softmax-lite: p = exp2(s); per-fi P bounce via 2KB/wave buffer
        bf16x8 pf[2][2];
        #pragma unroll
        for (int fi = 0; fi < 2; fi++) {
            float ts[4];
            #pragma unroll
            for (int kb = 0; kb < 4; kb++) {
                float p0 = EXP2(s[fi][kb][0]);
                float p1 = EXP2(s[fi][kb][1]);
                float p2 = EXP2(s[fi][kb][2]);
                float p3 = EXP2(s[fi][kb][3]);
                ts[kb] = (p0 + p1) + (p2 + p3);
                bf16x4 pb;
                pb[0] = (__bf16)p0; pb[1] = (__bf16)p1;
                pb[2] = (__bf16)p2; pb[3] = (__bf16)p3;
                *(bf16x4*)(PlB + pwoff[kb]) = pb;
            }
            lrow[fi] += (ts[0] + ts[1]) + (ts[2] + ts[3]);
            #pragma unroll
            for (int ks = 0; ks < 2; ks++)
                pf[fi][ks] = *(const bf16x8*)(PlB + proff[ks]);
        }
        // O += V^T-as-A * P-as-B
        __builtin_amdgcn_s_setprio(1);
        #pragma unroll
        for (int dt = 0; dt < 4; dt++) {
            int row = dt * 16 + ql;
            int swz = (row & 7) << 4;
            bf16x8 vf0 = *(const bf16x8*)(VsB + row * 128 + ((g * 16) ^ swz));
            bf16x8 vf1 = *(const bf16x8*)(VsB + row * 128 + ((64 + g * 16) ^ swz));
            #pragma unroll
            for (int fi = 0; fi < 2; fi++) {
                oacc[fi][dt] = __builtin_amdgcn_mfma_f32_16x16x32_bf16(vf0, pf[fi][0], oacc[fi][dt], 0, 0, 0);
                oacc[fi][dt] = __builtin_amdgcn_mfma_f32_16x16x32_bf16(vf1, pf[fi][1], oacc[fi][dt], 0, 0, 0);
            }
        }
        __builtin_amdgcn_s_setprio(0);

        mcur = mnxt;
        __syncthreads();   // drains vmcnt: next tile's LDS is ready for t+1
    }

    // epilogue: finish row-sums (reduce over g), normalize, bounce via LDS
    #pragma unroll
    for (int fi = 0; fi < 2; fi++) {
        lrow[fi] += __shfl_xor(lrow[fi], 16, 64);
        lrow[fi] += __shfl_xor(lrow[fi], 32, 64);
        float inv = 1.f / lrow[fi];
        #pragma unroll
        for (int dt = 0; dt < 4; dt++) {
            bf16x4 ob;
            ob[0] = (__bf16)(oacc[fi][dt][0] * inv);
            ob[1] = (__bf16)(oacc[fi][dt][1] * inv);
            ob[2] = (__bf16)(oacc[fi][dt][2] * inv);
            ob[3] = (__bf16)(oacc[fi][dt][3] * inv);
            *(bf16x4*)(PlB + ql * 128 + ((dt * 32 + g * 8) ^ ((ql & 7) << 4))) = ob;
        }
        int rr = lane >> 2;
        int q = qw + fi * 16 + rr;
        #pragma unroll
        for (int pass = 0; pass < 2; pass++) {
            int cc = (lane & 3) + pass * 4;
            int4 val = *(const int4*)(PlB + rr * 128 + ((cc * 16) ^ ((rr & 7) << 4)));
            *(int4*)&O[((size_t)(b * 2048 + q)) * 1024 + h * 64 + cc * 8] = val;
        }
    }
}

// ---------------------------------------------------------------------------
// LayerNorm over last dim (1024), row per block, bf16 in / f32 out
// ---------------------------------------------------------------------------
__global__ __launch_bounds__(256) void ln_k(
    const u16* __restrict__ X, const float* __restrict__ gamma,
    const float* __restrict__ beta, float* __restrict__ out)
{
    const int row = blockIdx.x, tid = threadIdx.x;
    ushort4 u = ((const ushort4*)(X + (size_t)row * 1024))[tid];
    float v0 = bf2f(u.x), v1 = bf2f(u.y), v2 = bf2f(u.z), v3 = bf2f(u.w);
    float s = (v0 + v1) + (v2 + v3);
    float s2 = (v0 * v0 + v1 * v1) + (v2 * v2 + v3 * v3);
    #pragma unroll
    for (int off = 1; off < 64; off <<= 1) {
        s  += __shfl_xor(s, off, 64);
        s2 += __shfl_xor(s2, off, 64);
    }
    __shared__ float ss[4], ss2[4];
    int wid = tid >> 6;
    if ((tid & 63) == 0) { ss[wid] = s; ss2[wid] = s2; }
    __syncthreads();
    s = ss[0] + ss[1] + ss[2] + ss[3];
    s2 = ss2[0] + ss2[1] + ss2[2] + ss2[3];
    float mean = s * (1.f / 1024.f);
    float var = s2 * (1.f / 1024.f) - mean * mean;
    float rstd = rsqrtf(var + 1e-5f);
    float4 gm = ((const float4*)gamma)[tid];
    float4 be = ((const float4*)beta)[tid];
    float4 o;
    o.x = (v0 - mean) * rstd * gm.x + be.x;
    o.y = (v1 - mean) * rstd * gm.y + be.y;
    o.z = (v2 - mean) * rstd * gm.z + be.z;
    o.w = (v3 - mean) * rstd * gm.w + be.w;
    ((float4*)(out + (size_t)row * 1024))[tid] = o;
}

// ---------------------------------------------------------------------------
extern "C" void kernel_launch(void* const* d_in, const int* in_sizes, int n_in,
                              void* d_out, int out_size, void* d_ws, size_t ws_size,
                              hipStream_t stream)
{
    const float* queries = (const float*)d_in[0];
    const float* keys    = (const float*)d_in[1];
    const float* values  = (const float*)d_in[2];
    const int*   mask    = (const int*)d_in[3];
    const float* Wq = (const float*)d_in[4];
    const float* bq = (const float*)d_in[5];
    const float* Wk = (const float*)d_in[6];
    const float* bk = (const float*)d_in[7];
    const float* Wv = (const float*)d_in[8];
    const float* bv = (const float*)d_in[9];
    const float* Wo = (const float*)d_in[10];
    const float* bo = (const float*)d_in[11];
    const float* gamma = (const float*)d_in[12];
    const float* beta  = (const float*)d_in[13];

    u16* ws = (u16*)d_ws;
    u16* Wt = ws;                       // 4 x 1048576 u16 (8 MB)
    u16* Qp = ws + 4 * 1048576;         // 8388608 u16 each
    u16* Kp = Qp + 8388608;
    u16* Vt = Kp + 8388608;
    u16* O  = Vt + 8388608;
    u16* X  = Qp;                       // alias: Qp dead after attention (bf16 X)

    // Q pre-scale folds 1/sqrt(64) * log2(e) so softmax runs in exp2 domain
    const float qscale = 0.125f * 1.44269504088896f;

    transpose4<<<dim3(32, 32, 4), 256, 0, stream>>>(Wq, Wk, Wv, Wo, Wt);
    gemm_bt<0, true ><<<dim3(64, 8), 256, 0, stream>>>(queries, Wt,           bq, nullptr, Qp, qscale);
    gemm_bt<0, true ><<<dim3(64, 8), 256, 0, stream>>>(keys,    Wt + 1048576, bk, nullptr, Kp, 1.0f);
    gemm_bt<1, true ><<<dim3(64, 8), 256, 0, stream>>>(values,  Wt + 2097152, bv, nullptr, Vt, 1.0f);
    attn_k<<<dim3(1024), 256, 0, stream>>>(Qp, Kp, Vt, mask, O);
    gemm_bt<2, false><<<dim3(64, 8), 256, 0, stream>>>(O, Wt + 3145728, bo, queries, X, 1.0f);
    ln_k<<<8192, 256, 0, stream>>>(X, gamma, beta, (float*)d_out);
}

// Round 9
// 238.571 us; speedup vs baseline: 1.3056x; 1.0060x over previous
//
#include <hip/hip_runtime.h>

typedef __bf16 bf16x8 __attribute__((ext_vector_type(8)));
typedef __bf16 bf16x4 __attribute__((ext_vector_type(4)));
typedef float f32x4 __attribute__((ext_vector_type(4)));
typedef unsigned short u16;

#if __has_builtin(__builtin_amdgcn_exp2f)
#define EXP2(x) __builtin_amdgcn_exp2f(x)
#else
#define EXP2(x) exp2f(x)
#endif

__device__ __forceinline__ float bf2f(u16 u){
    union { unsigned int i; float f; } x; x.i = ((unsigned int)u) << 16; return x.f;
}
__device__ __forceinline__ u16 f2bf(float f){
    union { float f; unsigned int i; } x; x.f = f;
    unsigned int r = x.i + 0x7fff + ((x.i >> 16) & 1);
    return (u16)(r >> 16);
}
__device__ __forceinline__ int4 cvt8(const float4 a, const float4 b){
    union { u16 h[8]; int4 v; } u;
    u.h[0] = f2bf(a.x); u.h[1] = f2bf(a.y); u.h[2] = f2bf(a.z); u.h[3] = f2bf(a.w);
    u.h[4] = f2bf(b.x); u.h[5] = f2bf(b.y); u.h[6] = f2bf(b.z); u.h[7] = f2bf(b.w);
    return u.v;
}
// async global->LDS, 16B per lane; dest is wave-uniform base + lane*16 (linear)
__device__ __forceinline__ void gload_lds16(const void* g, void* l){
    __builtin_amdgcn_global_load_lds(
        (const __attribute__((address_space(1))) unsigned int*)g,
        (__attribute__((address_space(3))) unsigned int*)l, 16, 0, 0);
}

// ---------------------------------------------------------------------------
// Transpose 4 x [1024][1024] f32 weights -> bf16 Wt [N][K]
// ---------------------------------------------------------------------------
__global__ __launch_bounds__(256) void transpose4(
    const float* __restrict__ w0, const float* __restrict__ w1,
    const float* __restrict__ w2, const float* __restrict__ w3,
    u16* __restrict__ out)
{
    __shared__ float tile[32][33];
    int mat = blockIdx.z;
    const float* in = (mat == 0) ? w0 : (mat == 1) ? w1 : (mat == 2) ? w2 : w3;
    u16* o = out + (size_t)mat * 1048576;
    int bx = blockIdx.x * 32, by = blockIdx.y * 32;
    int tx = threadIdx.x & 31, ty = threadIdx.x >> 5; // 32 x 8
    #pragma unroll
    for (int i = 0; i < 32; i += 8)
        tile[ty + i][tx] = in[(size_t)(by + ty + i) * 1024 + bx + tx];
    __syncthreads();
    #pragma unroll
    for (int i = 0; i < 32; i += 8)
        o[(size_t)(bx + ty + i) * 1024 + by + tx] = f2bf(tile[tx][ty + i]);
}

// ---------------------------------------------------------------------------
// GEMM: C = A(8192x1024) * Bt(1024x1024)^T + bias, store per MODE
// AF32: A is f32 (converted to bf16 during LDS staging); else A is bf16.
// MODE 0: Q/K -> [b][h][q][d] bf16 (scaled)   MODE 1: V -> [b][h][d][q] bf16
// MODE 2: bf16 row-major + f32 residual
// ---------------------------------------------------------------------------
template<int MODE, bool AF32>
__global__ __launch_bounds__(256) void gemm_bt(
    const void* __restrict__ Av, const u16* __restrict__ Bt,
    const float* __restrict__ bias, const float* __restrict__ resid,
    void* __restrict__ Cv, float scale)
{
    constexpr int K = 1024;
    __shared__ alignas(16) u16 As[2][128][32];
    __shared__ alignas(16) u16 Bs[2][128][32];
    const int tid = threadIdx.x;
    const int lane = tid & 63, wid = tid >> 6;
    const int wm = wid >> 1, wn = wid & 1;
    const int m0 = blockIdx.x * 128, n0 = blockIdx.y * 128;
    const int r0 = tid >> 2;            // 0..63
    const int kc = (tid & 3) * 8;       // 0,8,16,24
    const int fr = lane & 15, fk = (lane >> 4) * 8;

    const float* Af0 = (const float*)Av + (size_t)(m0 + r0) * K + kc;
    const float* Af1 = Af0 + (size_t)64 * K;
    const u16*   Ah0 = (const u16*)Av + (size_t)(m0 + r0) * K + kc;
    const u16*   Ah1 = Ah0 + (size_t)64 * K;
    const u16* Brow0 = Bt + (size_t)(n0 + r0) * K + kc;
    const u16* Brow1 = Brow0 + (size_t)64 * K;

    int4 pa0, pa1, pb0, pb1;
    if constexpr (AF32) {
        pa0 = cvt8(((const float4*)Af0)[0], ((const float4*)Af0)[1]);
        pa1 = cvt8(((const float4*)Af1)[0], ((const float4*)Af1)[1]);
    } else {
        pa0 = *(const int4*)(Ah0);
        pa1 = *(const int4*)(Ah1);
    }
    pb0 = *(const int4*)(Brow0);
    pb1 = *(const int4*)(Brow1);
    *(int4*)&As[0][r0][kc]      = pa0;
    *(int4*)&As[0][r0 + 64][kc] = pa1;
    *(int4*)&Bs[0][r0][kc]      = pb0;
    *(int4*)&Bs[0][r0 + 64][kc] = pb1;
    __syncthreads();

    f32x4 acc[4][4] = {};
    constexpr int NT = K / 32;
    for (int t = 0; t < NT; ++t) {
        int cur = t & 1, nxt = cur ^ 1;
        if (t + 1 < NT) {
            if constexpr (AF32) {
                pa0 = cvt8(((const float4*)(Af0 + (t + 1) * 32))[0],
                           ((const float4*)(Af0 + (t + 1) * 32))[1]);
                pa1 = cvt8(((const float4*)(Af1 + (t + 1) * 32))[0],
                           ((const float4*)(Af1 + (t + 1) * 32))[1]);
            } else {
                pa0 = *(const int4*)(Ah0 + (t + 1) * 32);
                pa1 = *(const int4*)(Ah1 + (t + 1) * 32);
            }
            pb0 = *(const int4*)(Brow0 + (t + 1) * 32);
            pb1 = *(const int4*)(Brow1 + (t + 1) * 32);
        }
        bf16x8 af[4], bfr[4];
        #pragma unroll
        for (int i = 0; i < 4; i++) {
            af[i]  = *(const bf16x8*)&As[cur][wm * 64 + i * 16 + fr][fk];
            bfr[i] = *(const bf16x8*)&Bs[cur][wn * 64 + i * 16 + fr][fk];
        }
        #pragma unroll
        for (int mi = 0; mi < 4; mi++)
            #pragma unroll
            for (int ni = 0; ni < 4; ni++)
                acc[mi][ni] = __builtin_amdgcn_mfma_f32_16x16x32_bf16(
                    af[mi], bfr[ni], acc[mi][ni], 0, 0, 0);
        if (t + 1 < NT) {
            *(int4*)&As[nxt][r0][kc]      = pa0;
            *(int4*)&As[nxt][r0 + 64][kc] = pa1;
            *(int4*)&Bs[nxt][r0][kc]      = pb0;
            *(int4*)&Bs[nxt][r0 + 64][kc] = pb1;
        }
        __syncthreads();
    }

    #pragma unroll
    for (int ni = 0; ni < 4; ni++) {
        int col = n0 + wn * 64 + ni * 16 + fr;
        float bcol = bias[col];
        #pragma unroll
        for (int mi = 0; mi < 4; mi++) {
            #pragma unroll
            for (int r = 0; r < 4; r++) {
                int m = m0 + wm * 64 + mi * 16 + (lane >> 4) * 4 + r;
                float val = acc[mi][ni][r] + bcol;
                if (MODE == 2) {
                    val += resid[(size_t)m * 1024 + col];
                    ((u16*)Cv)[(size_t)m * 1024 + col] = f2bf(val);
                } else {
                    val *= scale;
                    int b = m >> 11, q = m & 2047;
                    int h = col >> 6, d = col & 63;
                    size_t base = (size_t)(b * 16 + h) * 131072;
                    if (MODE == 0) ((u16*)Cv)[base + (size_t)q * 64 + d] = f2bf(val);
                    else           ((u16*)Cv)[base + (size_t)d * 2048 + q] = f2bf(val);
                }
            }
        }
    }
}

// ---------------------------------------------------------------------------
// Flash attention v7: swapped QK^T with FUSED per-kb exp2 (softmax-lite has
// no cross-kb dependency -> S block never lives as 32 regs; transient f32x4).
// K fragments re-read per fi (cheap ds_read) to time-share the per-wave 2KB
// P buffer. Total regs target <=128 (4 waves/SIMD, whole 1024-block grid
// co-resident: LDS 4x40960 = exactly 160 KiB).
// Qp/Kp [bh][2048][64] (Q pre-scaled by 1/8*log2e), Vt [bh][64][2048]
// -> O [b][q][h*64+d] bf16
// ---------------------------------------------------------------------------
__global__ __launch_bounds__(256, 4) void attn_k(
    const u16* __restrict__ Qp, const u16* __restrict__ Kp,
    const u16* __restrict__ Vt, const int* __restrict__ mask,
    u16* __restrict__ O)
{
    __shared__ alignas(16) u16 Ks[2][64][64];   // [buf][kv][d], swizzled (16 KB)
    __shared__ alignas(16) u16 Vs[2][64][64];   // [buf][d][kv], swizzled (16 KB)
    __shared__ alignas(16) u16 Pl[4][16][64];   // per-wave 2KB P bounce (8 KB)

    // XCD-bijective swizzle: all 16 q-tiles of one bh share blockIdx%8 (same XCD)
    const int wg = blockIdx.x;                 // 0..1023
    const int xc = wg & 7;
    const int rm = wg >> 3;                    // 0..127
    const int qx = rm & 15;
    const int bh = (rm >> 4) * 8 + xc;         // bijective
    const int b = bh >> 4, h = bh & 15;
    const int q0 = qx * 128;
    const int tid = threadIdx.x, wid = tid >> 6, lane = tid & 63;
    const int ql = lane & 15, g = lane >> 4;
    const int qw = q0 + wid * 32;

    const u16* Qbh = Qp + (size_t)bh * 131072;
    const u16* Kbh = Kp + (size_t)bh * 131072;
    const u16* Vbh = Vt + (size_t)bh * 131072;
    const int* mrow = mask + b * 2048;

    char* KsB0 = (char*)Ks;
    char* VsB0 = (char*)Vs;
    char* PlB = (char*)Pl + wid * 2048;

    // Q fragments (B-operand layout): qf[fi][ks], q = qw + fi*16 + ql
    bf16x8 qf[2][2];
    #pragma unroll
    for (int fi = 0; fi < 2; fi++)
        #pragma unroll
        for (int ks = 0; ks < 2; ks++)
            qf[fi][ks] = *(const bf16x8*)&Qbh[(size_t)(qw + fi * 16 + ql) * 64 + ks * 32 + g * 8];

    f32x4 oacc[2][4] = {};
    float lrow[2] = {0.f, 0.f};               // per-lane partial row-sums
    const f32x4 kZero = {0.f, 0.f, 0.f, 0.f}; // persistent zero C operand

    // loop-invariant P LDS offsets (per-wave [16][64] buffer, row = ql)
    int pwoff[4], proff[2];
    #pragma unroll
    for (int kb = 0; kb < 4; kb++)
        pwoff[kb] = ql * 128 + ((kb * 32 + g * 8) ^ ((ql & 7) << 4));
    #pragma unroll
    for (int ks = 0; ks < 2; ks++)
        proff[ks] = ql * 128 + ((ks * 64 + g * 16) ^ ((ql & 7) << 4));

    // global_load_lds staging geometry: wave wid owns tile rows [wid*16, wid*16+16)
    // lane l -> dest byte = base + l*16; source chunk pre-XORed (involution)
    const int lrow8 = lane >> 3;                       // 0..7
    const int coff  = ((lane & 7) ^ lrow8) << 4;       // swizzled source byte chunk
    const int rb    = wid * 16;                        // wave's row base in tile

    auto stage = [&](int buf, int tt) {
        const size_t kv0 = (size_t)tt * 64;
        #pragma unroll
        for (int i = 0; i < 2; i++) {
            const int rt = rb + i * 8;                 // uniform row base
            gload_lds16((const char*)Kbh + (kv0 + rt + lrow8) * 128 + coff,
                        KsB0 + buf * 8192 + rt * 128);
            gload_lds16((const char*)Vbh + (size_t)(rt + lrow8) * 4096 + kv0 * 2 + coff,
                        VsB0 + buf * 8192 + rt * 128);
        }
    };

    // prologue: stage tile 0 into buf 0 (barrier below drains vmcnt)
    stage(0, 0);
    int mcur = mrow[lane];
    __syncthreads();

    for (int t = 0; t < 32; ++t) {
        const int cur = t & 1, nxt = cur ^ 1;
        char* KsB = KsB0 + cur * 8192;
        char* VsB = VsB0 + cur * 8192;
        int mnxt = 1;
        // issue next tile's async loads now; they fly under this tile's compute
        if (t < 31) {
            stage(nxt, t + 1);
            mnxt = mrow[(t + 1) * 64 + lane];
        }
        const bool anym = (__ballot(mcur == 0) != 0ull);

        // QK^T + fused softmax-lite, one q-frag at a time (P buffer time-shared)
        bf16x8 pf[2][2];
        #pragma unroll
        for (int fi = 0; fi < 2; fi++) {
            float ts = 0.f;
            __builtin_amdgcn_s_setprio(1);
            #pragma unroll
            for (int kb = 0; kb < 4; kb++) {
                const int row = kb * 16 + ql;
                const int swz = (row & 7) << 4;
                bf16x8 kf0 = *(const bf16x8*)(KsB + row * 128 + ((g * 16) ^ swz));
                bf16x8 kf1 = *(const bf16x8*)(KsB + row * 128 + ((64 + g * 16) ^ swz));
                f32x4 a = __builtin_amdgcn_mfma_f32_16x16x32_bf16(kf0, qf[fi][0], kZero, 0, 0, 0);
                a = __builtin_amdgcn_mfma_f32_16x16x32_bf16(kf1, qf[fi][1], a, 0, 0, 0);
                if (anym) {
                    int4 mi = *(const int4*)&mrow[t * 64 + kb * 16 + g * 4];
                    a[0] += mi.x ? 0.f : -1e30f;
                    a[1] += mi.y ? 0.f : -1e30f;
                    a[2] += mi.z ? 0.f : -1e30f;
                    a[3] += mi.w ? 0.f : -1e30f;
                }
                float p0 = EXP2(a[0]);
                float p1 = EXP2(a[1]);
                float p2 = EXP2(a[2]);
                float p3 = EXP2(a[3]);
                ts += (p0 + p1) + (p2 + p3);
                bf16x4 pb;
                pb[0] = (__bf16)p0; pb[1] = (__bf16)p1;
                pb[2] = (__bf16)p2; pb[3] = (__bf16)p3;
                *(bf16x4*)(PlB + pwoff[kb]) = pb;
            }
            __builtin_amdgcn_s_setprio(0);
            lrow[fi] += ts;
            pf[fi][0] = *(const bf16x8*)(PlB + proff[0]);
            pf[fi][1] = *(const bf16x8*)(PlB + proff[1]);
        }

        // O += V^T-as-A * P-as-B
        __builtin_amdgcn_s_setprio(1);
        #pragma unroll
        for (int dt = 0; dt < 4; dt++) {
            int row = dt * 16 + ql;
            int swz = (row & 7) << 4;
            bf16x8 vf0 = *(const bf16x8*)(VsB + row * 128 + ((g * 16) ^ swz));
            bf16x8 vf1 = *(const bf16x8*)(VsB + row * 128 + ((64 + g * 16) ^ swz));
            #pragma unroll
            for (int fi = 0; fi < 2; fi++) {
                oacc[fi][dt] = __builtin_amdgcn_mfma_f32_16x16x32_bf16(vf0, pf[fi][0], oacc[fi][dt], 0, 0, 0);
                oacc[fi][dt] = __builtin_amdgcn_mfma_f32_16x16x32_bf16(vf1, pf[fi][1], oacc[fi][dt], 0, 0, 0);
            }
        }
        __builtin_amdgcn_s_setprio(0);

        mcur = mnxt;
        __syncthreads();   // drains vmcnt: next tile's LDS is ready for t+1
    }

    // epilogue: finish row-sums (reduce over g), normalize, bounce via LDS
    #pragma unroll
    for (int fi = 0; fi < 2; fi++) {
        lrow[fi] += __shfl_xor(lrow[fi], 16, 64);
        lrow[fi] += __shfl_xor(lrow[fi], 32, 64);
        float inv = 1.f / lrow[fi];
        #pragma unroll
        for (int dt = 0; dt < 4; dt++) {
            bf16x4 ob;
            ob[0] = (__bf16)(oacc[fi][dt][0] * inv);
            ob[1] = (__bf16)(oacc[fi][dt][1] * inv);
            ob[2] = (__bf16)(oacc[fi][dt][2] * inv);
            ob[3] = (__bf16)(oacc[fi][dt][3] * inv);
            *(bf16x4*)(PlB + ql * 128 + ((dt * 32 + g * 8) ^ ((ql & 7) << 4))) = ob;
        }
        int rr = lane >> 2;
        int q = qw + fi * 16 + rr;
        #pragma unroll
        for (int pass = 0; pass < 2; pass++) {
            int cc = (lane & 3) + pass * 4;
            int4 val = *(const int4*)(PlB + rr * 128 + ((cc * 16) ^ ((rr & 7) << 4)));
            *(int4*)&O[((size_t)(b * 2048 + q)) * 1024 + h * 64 + cc * 8] = val;
        }
    }
}

// ---------------------------------------------------------------------------
// LayerNorm over last dim (1024), row per block, bf16 in / f32 out
// ---------------------------------------------------------------------------
__global__ __launch_bounds__(256) void ln_k(
    const u16* __restrict__ X, const float* __restrict__ gamma,
    const float* __restrict__ beta, float* __restrict__ out)
{
    const int row = blockIdx.x, tid = threadIdx.x;
    ushort4 u = ((const ushort4*)(X + (size_t)row * 1024))[tid];
    float v0 = bf2f(u.x), v1 = bf2f(u.y), v2 = bf2f(u.z), v3 = bf2f(u.w);
    float s = (v0 + v1) + (v2 + v3);
    float s2 = (v0 * v0 + v1 * v1) + (v2 * v2 + v3 * v3);
    #pragma unroll
    for (int off = 1; off < 64; off <<= 1) {
        s  += __shfl_xor(s, off, 64);
        s2 += __shfl_xor(s2, off, 64);
    }
    __shared__ float ss[4], ss2[4];
    int wid = tid >> 6;
    if ((tid & 63) == 0) { ss[wid] = s; ss2[wid] = s2; }
    __syncthreads();
    s = ss[0] + ss[1] + ss[2] + ss[3];
    s2 = ss2[0] + ss2[1] + ss2[2] + ss2[3];
    float mean = s * (1.f / 1024.f);
    float var = s2 * (1.f / 1024.f) - mean * mean;
    float rstd = rsqrtf(var + 1e-5f);
    float4 gm = ((const float4*)gamma)[tid];
    float4 be = ((const float4*)beta)[tid];
    float4 o;
    o.x = (v0 - mean) * rstd * gm.x + be.x;
    o.y = (v1 - mean) * rstd * gm.y + be.y;
    o.z = (v2 - mean) * rstd * gm.z + be.z;
    o.w = (v3 - mean) * rstd * gm.w + be.w;
    ((float4*)(out + (size_t)row * 1024))[tid] = o;
}

// ---------------------------------------------------------------------------
extern "C" void kernel_launch(void* const* d_in, const int* in_sizes, int n_in,
                              void* d_out, int out_size, void* d_ws, size_t ws_size,
                              hipStream_t stream)
{
    const float* queries = (const float*)d_in[0];
    const float* keys    = (const float*)d_in[1];
    const float* values  = (const float*)d_in[2];
    const int*   mask    = (const int*)d_in[3];
    const float* Wq = (const float*)d_in[4];
    const float* bq = (const float*)d_in[5];
    const float* Wk = (const float*)d_in[6];
    const float* bk = (const float*)d_in[7];
    const float* Wv = (const float*)d_in[8];
    const float* bv = (const float*)d_in[9];
    const float* Wo = (const float*)d_in[10];
    const float* bo = (const float*)d_in[11];
    const float* gamma = (const float*)d_in[12];
    const float* beta  = (const float*)d_in[13];

    u16* ws = (u16*)d_ws;
    u16* Wt = ws;                       // 4 x 1048576 u16 (8 MB)
    u16* Qp = ws + 4 * 1048576;         // 8388608 u16 each
    u16* Kp = Qp + 8388608;
    u16* Vt = Kp + 8388608;
    u16* O  = Vt + 8388608;
    u16* X  = Qp;                       // alias: Qp dead after attention (bf16 X)

    // Q pre-scale folds 1/sqrt(64) * log2(e) so softmax runs in exp2 domain
    const float qscale = 0.125f * 1.44269504088896f;

    transpose4<<<dim3(32, 32, 4), 256, 0, stream>>>(Wq, Wk, Wv, Wo, Wt);
    gemm_bt<0, true ><<<dim3(64, 8), 256, 0, stream>>>(queries, Wt,           bq, nullptr, Qp, qscale);
    gemm_bt<0, true ><<<dim3(64, 8), 256, 0, stream>>>(keys,    Wt + 1048576, bk, nullptr, Kp, 1.0f);
    gemm_bt<1, true ><<<dim3(64, 8), 256, 0, stream>>>(values,  Wt + 2097152, bv, nullptr, Vt, 1.0f);
    attn_k<<<dim3(1024), 256, 0, stream>>>(Qp, Kp, Vt, mask, O);
    gemm_bt<2, false><<<dim3(64, 8), 256, 0, stream>>>(O, Wt + 3145728, bo, queries, X, 1.0f);
    ln_k<<<8192, 256, 0, stream>>>(X, gamma, beta, (float*)d_out);
}

// Round 10
// 237.708 us; speedup vs baseline: 1.3103x; 1.0036x over previous
//
#include <hip/hip_runtime.h>

typedef __bf16 bf16x8 __attribute__((ext_vector_type(8)));
typedef __bf16 bf16x4 __attribute__((ext_vector_type(4)));
typedef float f32x4 __attribute__((ext_vector_type(4)));
typedef unsigned short u16;

#if __has_builtin(__builtin_amdgcn_exp2f)
#define EXP2(x) __builtin_amdgcn_exp2f(x)
#else
#define EXP2(x) exp2f(x)
#endif

__device__ __forceinline__ float bf2f(u16 u){
    union { unsigned int i; float f; } x; x.i = ((unsigned int)u) << 16; return x.f;
}
__device__ __forceinline__ u16 f2bf(float f){
    union { float f; unsigned int i; } x; x.f = f;
    unsigned int r = x.i + 0x7fff + ((x.i >> 16) & 1);
    return (u16)(r >> 16);
}
__device__ __forceinline__ int4 cvt8(const float4 a, const float4 b){
    union { u16 h[8]; int4 v; } u;
    u.h[0] = f2bf(a.x); u.h[1] = f2bf(a.y); u.h[2] = f2bf(a.z); u.h[3] = f2bf(a.w);
    u.h[4] = f2bf(b.x); u.h[5] = f2bf(b.y); u.h[6] = f2bf(b.z); u.h[7] = f2bf(b.w);
    return u.v;
}
// async global->LDS, 16B per lane; dest is wave-uniform base (HW adds lane*16)
__device__ __forceinline__ void gload_lds16(const void* g, void* l){
    __builtin_amdgcn_global_load_lds(
        (const __attribute__((address_space(1))) unsigned int*)g,
        (__attribute__((address_space(3))) unsigned int*)l, 16, 0, 0);
}

// ---------------------------------------------------------------------------
// Transpose 4 x [1024][1024] f32 weights -> bf16 Wt [N][K]
// ---------------------------------------------------------------------------
__global__ __launch_bounds__(256) void transpose4(
    const float* __restrict__ w0, const float* __restrict__ w1,
    const float* __restrict__ w2, const float* __restrict__ w3,
    u16* __restrict__ out)
{
    __shared__ float tile[32][33];
    int mat = blockIdx.z;
    const float* in = (mat == 0) ? w0 : (mat == 1) ? w1 : (mat == 2) ? w2 : w3;
    u16* o = out + (size_t)mat * 1048576;
    int bx = blockIdx.x * 32, by = blockIdx.y * 32;
    int tx = threadIdx.x & 31, ty = threadIdx.x >> 5; // 32 x 8
    #pragma unroll
    for (int i = 0; i < 32; i += 8)
        tile[ty + i][tx] = in[(size_t)(by + ty + i) * 1024 + bx + tx];
    __syncthreads();
    #pragma unroll
    for (int i = 0; i < 32; i += 8)
        o[(size_t)(bx + ty + i) * 1024 + by + tx] = f2bf(tile[tx][ty + i]);
}

// ---------------------------------------------------------------------------
// GEMM v2 (m97-style): C = A(8192x1024) * Bt(1024x1024)^T + bias.
// B staged via global_load_lds (bf16); A via global_load_lds when bf16
// (MODE 2) or reg-staged with f32->bf16 cvt (AF32). Chunk-XOR LDS swizzle
// (c ^= row&3) on both staging and fragment reads. Epilogue repacks through
// a 32KB Ct LDS tile (aliasing As/Bs) for fully coalesced int4 stores.
// MODE 0: Q/K -> [b][h][q][d] bf16 (scaled)   MODE 1: V -> [b][h][d][q] bf16
// MODE 2: bf16 row-major + f32 residual
// Grid: 1D 512, XCD-grouped so the 8 n-tiles of one m-tile share an XCD L2.
// ---------------------------------------------------------------------------
template<int MODE, bool AF32>
__global__ __launch_bounds__(256) void gemm_bt(
    const void* __restrict__ Av, const u16* __restrict__ Bt,
    const float* __restrict__ bias, const float* __restrict__ resid,
    void* __restrict__ Cv, float scale)
{
    constexpr int K = 1024;
    __shared__ alignas(16) u16 smem[16384];      // 32 KB: As(16K) | Bs(16K)
    char* const AB = (char*)smem;
    auto Abase = [&](int buf){ return AB + buf * 8192; };
    auto Bbase = [&](int buf){ return AB + 16384 + buf * 8192; };

    const int tid = threadIdx.x;
    const int lane = tid & 63, wid = tid >> 6;
    const int wm = wid >> 1, wn = wid & 1;

    // XCD-grouped decomposition: m-tile = mhi*8 + (wg&7) -> same XCD shares A
    const int wg = blockIdx.x;                   // 0..511
    const int xcd = wg & 7, rest = wg >> 3;
    const int ntile = rest & 7, mhi = rest >> 3;
    const int m0 = (mhi * 8 + xcd) * 128;
    const int n0 = ntile * 128;

    const int r0 = tid >> 2;            // 0..63
    const int kc = (tid & 3) * 8;       // u16 col 0,8,16,24
    const int kcB = (tid & 3) * 16;     // byte col
    const int fr = lane & 15;
    const int fkB = (lane >> 4) * 16;   // fragment byte col

    const float* Af0 = (const float*)Av + (size_t)(m0 + r0) * K + kc;
    const float* Af1 = Af0 + (size_t)64 * K;
    const u16*   Ah  = (const u16*)Av;

    // staging geometry: wave wid stages rows [wid*32, wid*32+32), 16 rows/inst
    // lane l covers row rt+(l>>2), stored chunk l&3 = logical chunk ^ (row&3)
    const int srow = lane >> 2;         // 0..15 within 16-row group
    auto stageB = [&](int buf, int tcol) {
        #pragma unroll
        for (int i = 0; i < 2; i++) {
            int rt = wid * 32 + i * 16;
            int r = rt + srow;
            gload_lds16(Bt + (size_t)(n0 + r) * K + tcol + ((lane & 3) ^ (r & 3)) * 8,
                        Bbase(buf) + rt * 64);
        }
    };
    auto stageA16 = [&](int buf, int tcol) {     // bf16 A (MODE 2)
        #pragma unroll
        for (int i = 0; i < 2; i++) {
            int rt = wid * 32 + i * 16;
            int r = rt + srow;
            gload_lds16(Ah + (size_t)(m0 + r) * K + tcol + ((lane & 3) ^ (r & 3)) * 8,
                        Abase(buf) + rt * 64);
        }
    };
    const int aswz = ((r0 & 3) << 4);

    // prologue: stage tile 0 into buf 0
    stageB(0, 0);
    if constexpr (AF32) {
        int4 w0 = cvt8(((const float4*)Af0)[0], ((const float4*)Af0)[1]);
        int4 w1 = cvt8(((const float4*)Af1)[0], ((const float4*)Af1)[1]);
        *(int4*)(Abase(0) + r0 * 64 + (kcB ^ aswz)) = w0;
        *(int4*)(Abase(0) + (r0 + 64) * 64 + (kcB ^ aswz)) = w1;
    } else {
        stageA16(0, 0);
    }
    __syncthreads();

    f32x4 acc[4][4] = {};
    constexpr int NT = K / 32;
    for (int t = 0; t < NT; ++t) {
        const int cur = t & 1, nxt = cur ^ 1;
        float4 a00, a01, a10, a11;
        if (t + 1 < NT) {
            stageB(nxt, (t + 1) * 32);
            if constexpr (AF32) {
                a00 = ((const float4*)(Af0 + (t + 1) * 32))[0];
                a01 = ((const float4*)(Af0 + (t + 1) * 32))[1];
                a10 = ((const float4*)(Af1 + (t + 1) * 32))[0];
                a11 = ((const float4*)(Af1 + (t + 1) * 32))[1];
            } else {
                stageA16(nxt, (t + 1) * 32);
            }
        }
        bf16x8 af[4], bfr[4];
        #pragma unroll
        for (int i = 0; i < 4; i++) {
            int ra = wm * 64 + i * 16 + fr;
            int rb = wn * 64 + i * 16 + fr;
            af[i]  = *(const bf16x8*)(Abase(cur) + ra * 64 + (fkB ^ ((ra & 3) << 4)));
            bfr[i] = *(const bf16x8*)(Bbase(cur) + rb * 64 + (fkB ^ ((rb & 3) << 4)));
        }
        #pragma unroll
        for (int mi = 0; mi < 4; mi++)
            #pragma unroll
            for (int ni = 0; ni < 4; ni++)
                acc[mi][ni] = __builtin_amdgcn_mfma_f32_16x16x32_bf16(
                    af[mi], bfr[ni], acc[mi][ni], 0, 0, 0);
        if (t + 1 < NT) {
            if constexpr (AF32) {
                *(int4*)(Abase(nxt) + r0 * 64 + (kcB ^ aswz)) = cvt8(a00, a01);
                *(int4*)(Abase(nxt) + (r0 + 64) * 64 + (kcB ^ aswz)) = cvt8(a10, a11);
            }
        }
        __syncthreads();
    }

    // epilogue: acc -> Ct (bf16, swizzled, aliases As/Bs) -> coalesced stores
    char* const CtB = AB;   // [128][128] u16 = 32 KB
    #pragma unroll
    for (int ni = 0; ni < 4; ni++) {
        int nn = wn * 64 + ni * 16 + fr;
        float bcol = bias[n0 + nn];
        #pragma unroll
        for (int mi = 0; mi < 4; mi++) {
            #pragma unroll
            for (int r = 0; r < 4; r++) {
                int mm = wm * 64 + mi * 16 + (lane >> 4) * 4 + r;
                float val = acc[mi][ni][r] + bcol;
                if (MODE == 2) val += resid[(size_t)(m0 + mm) * 1024 + n0 + nn];
                else val *= scale;
                int row  = (MODE == 1) ? nn : mm;
                int colb = ((MODE == 1) ? mm : nn) * 2;
                *(u16*)(CtB + row * 256 +
                        ((colb & 15) | ((((colb >> 4)) ^ (row & 7)) << 4))) = f2bf(val);
            }
        }
    }
    __syncthreads();
    #pragma unroll
    for (int p = 0; p < 8; p++) {
        int idx = p * 256 + tid;
        int row = idx >> 4, ck = idx & 15;
        int4 val = *(const int4*)(CtB + row * 256 + ((ck ^ (row & 7)) << 4));
        if (MODE == 1) {
            int n = n0 + row, m = m0 + ck * 8;
            int h = n >> 6, d = n & 63, bb = m >> 11, q = m & 2047;
            *(int4*)&((u16*)Cv)[(size_t)(bb * 16 + h) * 131072 + (size_t)d * 2048 + q] = val;
        } else if (MODE == 0) {
            int m = m0 + row, n = n0 + ck * 8;
            int h = n >> 6, d = n & 63, bb = m >> 11, q = m & 2047;
            *(int4*)&((u16*)Cv)[(size_t)(bb * 16 + h) * 131072 + (size_t)q * 64 + d] = val;
        } else {
            int m = m0 + row, n = n0 + ck * 8;
            *(int4*)&((u16*)Cv)[(size_t)m * 1024 + n] = val;
        }
    }
}

// ---------------------------------------------------------------------------
// Flash attention v7 (unchanged from R9): swapped QK^T with fused per-kb exp2,
// softmax-lite, gload_lds K/V staging, XCD-bijective swizzle, 4 blocks/CU.
// ---------------------------------------------------------------------------
__global__ __launch_bounds__(256, 4) void attn_k(
    const u16* __restrict__ Qp, const u16* __restrict__ Kp,
    const u16* __restrict__ Vt, const int* __restrict__ mask,
    u16* __restrict__ O)
{
    __shared__ alignas(16) u16 Ks[2][64][64];
    __shared__ alignas(16) u16 Vs[2][64][64];
    __shared__ alignas(16) u16 Pl[4][16][64];

    const int wg = blockIdx.x;
    const int xc = wg & 7;
    const int rm = wg >> 3;
    const int qx = rm & 15;
    const int bh = (rm >> 4) * 8 + xc;
    const int b = bh >> 4, h = bh & 15;
    const int q0 = qx * 128;
    const int tid = threadIdx.x, wid = tid >> 6, lane = tid & 63;
    const int ql = lane & 15, g = lane >> 4;
    const int qw = q0 + wid * 32;

    const u16* Qbh = Qp + (size_t)bh * 131072;
    const u16* Kbh = Kp + (size_t)bh * 131072;
    const u16* Vbh = Vt + (size_t)bh * 131072;
    const int* mrow = mask + b * 2048;

    char* KsB0 = (char*)Ks;
    char* VsB0 = (char*)Vs;
    char* PlB = (char*)Pl + wid * 2048;

    bf16x8 qf[2][2];
    #pragma unroll
    for (int fi = 0; fi < 2; fi++)
        #pragma unroll
        for (int ks = 0; ks < 2; ks++)
            qf[fi][ks] = *(const bf16x8*)&Qbh[(size_t)(qw + fi * 16 + ql) * 64 + ks * 32 + g * 8];

    f32x4 oacc[2][4] = {};
    float lrow[2] = {0.f, 0.f};
    const f32x4 kZero = {0.f, 0.f, 0.f, 0.f};

    int pwoff[4], proff[2];
    #pragma unroll
    for (int kb = 0; kb < 4; kb++)
        pwoff[kb] = ql * 128 + ((kb * 32 + g * 8) ^ ((ql & 7) << 4));
    #pragma unroll
    for (int ks = 0; ks < 2; ks++)
        proff[ks] = ql * 128 + ((ks * 64 + g * 16) ^ ((ql & 7) << 4));

    const int lrow8 = lane >> 3;
    const int coff  = ((lane & 7) ^ lrow8) << 4;
    const int rb    = wid * 16;

    auto stage = [&](int buf, int tt) {
        const size_t kv0 = (size_t)tt * 64;
        #pragma unroll
        for (int i = 0; i < 2; i++) {
            const int rt = rb + i * 8;
            gload_lds16((const char*)Kbh + (kv0 + rt + lrow8) * 128 + coff,
                        KsB0 + buf * 8192 + rt * 128);
            gload_lds16((const char*)Vbh + (size_t)(rt + lrow8) * 4096 + kv0 * 2 + coff,
                        VsB0 + buf * 8192 + rt * 128);
        }
    };

    stage(0, 0);
    int mcur = mrow[lane];
    __syncthreads();

    for (int t = 0; t < 32; ++t) {
        const int cur = t & 1, nxt = cur ^ 1;
        char* KsB = KsB0 + cur * 8192;
        char* VsB = VsB0 + cur * 8192;
        int mnxt = 1;
        if (t < 31) {
            stage(nxt, t + 1);
            mnxt = mrow[(t + 1) * 64 + lane];
        }
        const bool anym = (__ballot(mcur == 0) != 0ull);

        bf16x8 pf[2][2];
        #pragma unroll
        for (int fi = 0; fi < 2; fi++) {
            float ts = 0.f;
            __builtin_amdgcn_s_setprio(1);
            #pragma unroll
            for (int kb = 0; kb < 4; kb++) {
                const int row = kb * 16 + ql;
                const int swz = (row & 7) << 4;
                bf16x8 kf0 = *(const bf16x8*)(KsB + row * 128 + ((g * 16) ^ swz));
                bf16x8 kf1 = *(const bf16x8*)(KsB + row * 128 + ((64 + g * 16) ^ swz));
                f32x4 a = __builtin_amdgcn_mfma_f32_16x16x32_bf16(kf0, qf[fi][0], kZero, 0, 0, 0);
                a = __builtin_amdgcn_mfma_f32_16x16x32_bf16(kf1, qf[fi][1], a, 0, 0, 0);
                if (anym) {
                    int4 mi = *(const int4*)&mrow[t * 64 + kb * 16 + g * 4];
                    a[0] += mi.x ? 0.f : -1e30f;
                    a[1] += mi.y ? 0.f : -1e30f;
                    a[2] += mi.z ? 0.f : -1e30f;
                    a[3] += mi.w ? 0.f : -1e30f;
                }
                float p0 = EXP2(a[0]);
                float p1 = EXP2(a[1]);
                float p2 = EXP2(a[2]);
                float p3 = EXP2(a[3]);
                ts += (p0 + p1) + (p2 + p3);
                bf16x4 pb;
                pb[0] = (__bf16)p0; pb[1] = (__bf16)p1;
                pb[2] = (__bf16)p2; pb[3] = (__bf16)p3;
                *(bf16x4*)(PlB + pwoff[kb]) = pb;
            }
            __builtin_amdgcn_s_setprio(0);
            lrow[fi] += ts;
            pf[fi][0] = *(const bf16x8*)(PlB + proff[0]);
            pf[fi][1] = *(const bf16x8*)(PlB + proff[1]);
        }

        __builtin_amdgcn_s_setprio(1);
        #pragma unroll
        for (int dt = 0; dt < 4; dt++) {
            int row = dt * 16 + ql;
            int swz = (row & 7) << 4;
            bf16x8 vf0 = *(const bf16x8*)(VsB + row * 128 + ((g * 16) ^ swz));
            bf16x8 vf1 = *(const bf16x8*)(VsB + row * 128 + ((64 + g * 16) ^ swz));
            #pragma unroll
            for (int fi = 0; fi < 2; fi++) {
                oacc[fi][dt] = __builtin_amdgcn_mfma_f32_16x16x32_bf16(vf0, pf[fi][0], oacc[fi][dt], 0, 0, 0);
                oacc[fi][dt] = __builtin_amdgcn_mfma_f32_16x16x32_bf16(vf1, pf[fi][1], oacc[fi][dt], 0, 0, 0);
            }
        }
        __builtin_amdgcn_s_setprio(0);

        mcur = mnxt;
        __syncthreads();
    }

    #pragma unroll
    for (int fi = 0; fi < 2; fi++) {
        lrow[fi] += __shfl_xor(lrow[fi], 16, 64);
        lrow[fi] += __shfl_xor(lrow[fi], 32, 64);
        float inv = 1.f / lrow[fi];
        #pragma unroll
        for (int dt = 0; dt < 4; dt++) {
            bf16x4 ob;
            ob[0] = (__bf16)(oacc[fi][dt][0] * inv);
            ob[1] = (__bf16)(oacc[fi][dt][1] * inv);
            ob[2] = (__bf16)(oacc[fi][dt][2] * inv);
            ob[3] = (__bf16)(oacc[fi][dt][3] * inv);
            *(bf16x4*)(PlB + ql * 128 + ((dt * 32 + g * 8) ^ ((ql & 7) << 4))) = ob;
        }
        int rr = lane >> 2;
        int q = qw + fi * 16 + rr;
        #pragma unroll
        for (int pass = 0; pass < 2; pass++) {
            int cc = (lane & 3) + pass * 4;
            int4 val = *(const int4*)(PlB + rr * 128 + ((cc * 16) ^ ((rr & 7) << 4)));
            *(int4*)&O[((size_t)(b * 2048 + q)) * 1024 + h * 64 + cc * 8] = val;
        }
    }
}

// ---------------------------------------------------------------------------
// LayerNorm over last dim (1024), row per block, bf16 in / f32 out
// ---------------------------------------------------------------------------
__global__ __launch_bounds__(256) void ln_k(
    const u16* __restrict__ X, const float* __restrict__ gamma,
    const float* __restrict__ beta, float* __restrict__ out)
{
    const int row = blockIdx.x, tid = threadIdx.x;
    ushort4 u = ((const ushort4*)(X + (size_t)row * 1024))[tid];
    float v0 = bf2f(u.x), v1 = bf2f(u.y), v2 = bf2f(u.z), v3 = bf2f(u.w);
    float s = (v0 + v1) + (v2 + v3);
    float s2 = (v0 * v0 + v1 * v1) + (v2 * v2 + v3 * v3);
    #pragma unroll
    for (int off = 1; off < 64; off <<= 1) {
        s  += __shfl_xor(s, off, 64);
        s2 += __shfl_xor(s2, off, 64);
    }
    __shared__ float ss[4], ss2[4];
    int wid = tid >> 6;
    if ((tid & 63) == 0) { ss[wid] = s; ss2[wid] = s2; }
    __syncthreads();
    s = ss[0] + ss[1] + ss[2] + ss[3];
    s2 = ss2[0] + ss2[1] + ss2[2] + ss2[3];
    float mean = s * (1.f / 1024.f);
    float var = s2 * (1.f / 1024.f) - mean * mean;
    float rstd = rsqrtf(var + 1e-5f);
    float4 gm = ((const float4*)gamma)[tid];
    float4 be = ((const float4*)beta)[tid];
    float4 o;
    o.x = (v0 - mean) * rstd * gm.x + be.x;
    o.y = (v1 - mean) * rstd * gm.y + be.y;
    o.z = (v2 - mean) * rstd * gm.z + be.z;
    o.w = (v3 - mean) * rstd * gm.w + be.w;
    ((float4*)(out + (size_t)row * 1024))[tid] = o;
}

// ---------------------------------------------------------------------------
extern "C" void kernel_launch(void* const* d_in, const int* in_sizes, int n_in,
                              void* d_out, int out_size, void* d_ws, size_t ws_size,
                              hipStream_t stream)
{
    const float* queries = (const float*)d_in[0];
    const float* keys    = (const float*)d_in[1];
    const float* values  = (const float*)d_in[2];
    const int*   mask    = (const int*)d_in[3];
    const float* Wq = (const float*)d_in[4];
    const float* bq = (const float*)d_in[5];
    const float* Wk = (const float*)d_in[6];
    const float* bk = (const float*)d_in[7];
    const float* Wv = (const float*)d_in[8];
    const float* bv = (const float*)d_in[9];
    const float* Wo = (const float*)d_in[10];
    const float* bo = (const float*)d_in[11];
    const float* gamma = (const float*)d_in[12];
    const float* beta  = (const float*)d_in[13];

    u16* ws = (u16*)d_ws;
    u16* Wt = ws;                       // 4 x 1048576 u16 (8 MB)
    u16* Qp = ws + 4 * 1048576;         // 8388608 u16 each
    u16* Kp = Qp + 8388608;
    u16* Vt = Kp + 8388608;
    u16* O  = Vt + 8388608;
    u16* X  = Qp;                       // alias: Qp dead after attention (bf16 X)

    // Q pre-scale folds 1/sqrt(64) * log2(e) so softmax runs in exp2 domain
    const float qscale = 0.125f * 1.44269504088896f;

    transpose4<<<dim3(32, 32, 4), 256, 0, stream>>>(Wq, Wk, Wv, Wo, Wt);
    gemm_bt<0, true ><<<dim3(512), 256, 0, stream>>>(queries, Wt,           bq, nullptr, Qp, qscale);
    gemm_bt<0, true ><<<dim3(512), 256, 0, stream>>>(keys,    Wt + 1048576, bk, nullptr, Kp, 1.0f);
    gemm_bt<1, true ><<<dim3(512), 256, 0, stream>>>(values,  Wt + 2097152, bv, nullptr, Vt, 1.0f);
    attn_k<<<dim3(1024), 256, 0, stream>>>(Qp, Kp, Vt, mask, O);
    gemm_bt<2, false><<<dim3(512), 256, 0, stream>>>(O, Wt + 3145728, bo, queries, X, 1.0f);
    ln_k<<<8192, 256, 0, stream>>>(X, gamma, beta, (float*)d_out);
}